// Round 6
// baseline (355.562 us; speedup 1.0000x reference)
//
#include <hip/hip_runtime.h>
#include <stdint.h>

// ---------------------------------------------------------------------------
// SSM: q=1x1 reduce + L2norm; ss = clamp(unfold7x7 * center); 3x chained 3x3
// conv (+BN+relu) per pixel; 1x1 + BN; residual; FFN (1x1,relu,1x1).
// B=8, C=256, MID=64, H=W=64.  bf16 MFMA 16x16x32 for all heavy GEMMs.
// R7: (a) k_out reverted to R5 shape (64 px/WG, wf[32]) — R6 re-tile regressed
//     12.5 us via doubled per-px weight traffic.  (b) encoder conv1 staging in
//     T14 order: cen preloaded once; per iter consume(ir) -> WRITE(ir+1 from
//     regs) -> ISSUE(ir+2) -> barrier, so global latency hides under MFMA.
// R5/R6 verified: streamed-ss ring 2 blocks/CU (129us), native f2bf (-4us).
// ---------------------------------------------------------------------------

typedef __attribute__((ext_vector_type(8))) __bf16 bf16x8;
typedef __attribute__((ext_vector_type(4))) float f32x4;

__device__ __forceinline__ ushort f2bf(float f) {
  __bf16 h = (__bf16)f;                 // RNE, compiler packs pairs
  return __builtin_bit_cast(ushort, h);
}
__device__ __forceinline__ float bfu(ushort h) {
  return __builtin_bit_cast(float, ((uint32_t)h) << 16);
}
__device__ __forceinline__ f32x4 mfma16(bf16x8 a, bf16x8 b, f32x4 c) {
  return __builtin_amdgcn_mfma_f32_16x16x32_bf16(a, b, c, 0, 0, 0);
}

union BV8 { uint4 v; ushort u[8]; };

// ---------------------------------------------------------------------------
// Workspace layout (bytes)
// ---------------------------------------------------------------------------
#define OFF_WRT 0u          // w_red_t  fp32 [256][64]            65536
#define OFF_WCB 65536u      // wc_b     bf16 [3][9][64][64]       221184
#define OFF_SHC 286720u     // shift_c  fp32 [3][64]              768
#define OFF_WOB 287488u     // w_out_b  bf16 [256][64]            32768
#define OFF_SHO 320256u     // shift_o  fp32 [256]                1024
#define OFF_WF1 321280u     // w_f1_b   bf16 [256][256]           131072
#define OFF_WF2 452352u     // w_f2_b   bf16 [256][256]           131072
#define OFF_QN  583424u     // q_n      bf16 [32768][64]          4194304
#define OFF_Y   4777728u    // y        bf16 [32768][64]          4194304

// ---------------------------------------------------------------------------
// Kernel 0: weight prep (fold BN, transpose, cast to bf16)
// ---------------------------------------------------------------------------
__global__ __launch_bounds__(256) void k_prep(
    const float* __restrict__ w_red, const float* __restrict__ w_c, const float* __restrict__ b_c,
    const float* __restrict__ bn_g, const float* __restrict__ bn_b, const float* __restrict__ bn_m,
    const float* __restrict__ bn_v, const float* __restrict__ w_out, const float* __restrict__ b_out,
    const float* __restrict__ bno_g, const float* __restrict__ bno_b, const float* __restrict__ bno_m,
    const float* __restrict__ bno_v, const float* __restrict__ w_f1, const float* __restrict__ w_f2,
    float* __restrict__ w_red_t, ushort* __restrict__ wc_b, float* __restrict__ shift_c,
    ushort* __restrict__ w_out_b, float* __restrict__ shift_o,
    ushort* __restrict__ w_f1_b, ushort* __restrict__ w_f2_b)
{
  int i = blockIdx.x * 256 + threadIdx.x;
  if (i < 16384) {                       // w_red_t[c][mid] = w_red[mid][c]
    int c = i >> 6, m = i & 63;
    w_red_t[i] = w_red[m * 256 + c];
    return;
  }
  i -= 16384;
  if (i < 110592) {                      // wc_b[s][tap][o][c] = w_c[s][o][c][du][dv] * bnscale
    int c = i & 63, o = (i >> 6) & 63, st = i >> 12;
    int tap = st % 9, s = st / 9;
    float sc = bn_g[s * 64 + o] * rsqrtf(bn_v[s * 64 + o] + 1e-5f);
    wc_b[i] = f2bf(w_c[((s * 64 + o) * 64 + c) * 9 + tap] * sc);
    return;
  }
  i -= 110592;
  if (i < 192) {                         // shift_c[s][o]
    int s = i >> 6, o = i & 63;
    float sc = bn_g[s * 64 + o] * rsqrtf(bn_v[s * 64 + o] + 1e-5f);
    shift_c[i] = (b_c[i] - bn_m[i]) * sc + bn_b[i];
    return;
  }
  i -= 192;
  if (i < 16384) {                       // w_out_b[o][c] (bno scale folded)
    int o = i >> 6;
    float sc = bno_g[o] * rsqrtf(bno_v[o] + 1e-5f);
    w_out_b[i] = f2bf(w_out[i] * sc);
    return;
  }
  i -= 16384;
  if (i < 256) {                         // shift_o[o]
    float sc = bno_g[i] * rsqrtf(bno_v[i] + 1e-5f);
    shift_o[i] = (b_out[i] - bno_m[i]) * sc + bno_b[i];
    return;
  }
  i -= 256;
  if (i < 65536) { w_f1_b[i] = f2bf(w_f1[i]); return; }
  i -= 65536;
  if (i < 65536) { w_f2_b[i] = f2bf(w_f2[i]); return; }
}

// ---------------------------------------------------------------------------
// Kernel 1: q = w_red @ x per pixel, L2-normalize over 64 mids -> q_n bf16
// ---------------------------------------------------------------------------
__global__ __launch_bounds__(256) void k_qnorm(
    const float* __restrict__ x, const float* __restrict__ w_red_t, ushort* __restrict__ qn)
{
  __shared__ float xs[64 * 64];     // [c][px]
  __shared__ float wls[64 * 64];    // [c][mid]
  __shared__ float part[64 * 16];   // [px][mq]
  __shared__ float sinv[64];

  const int tid = threadIdx.x;
  const int pix0 = blockIdx.x * 64;
  const int b = pix0 >> 12;
  const int hw0 = pix0 & 4095;
  const int pxq = tid & 15, mq = tid >> 4;
  const int lr = tid >> 2, lseg = tid & 3;

  float acc[4][4] = {};   // [mi][pi]

  for (int c0 = 0; c0 < 256; c0 += 64) {
    const float4* xg = (const float4*)(x + (size_t)(b * 256 + c0 + lr) * 4096 + hw0 + lseg * 16);
    float4* xd = (float4*)(xs + lr * 64 + lseg * 16);
    const float4* wg = (const float4*)(w_red_t + (c0 + lr) * 64 + lseg * 16);
    float4* wd = (float4*)(wls + lr * 64 + lseg * 16);
#pragma unroll
    for (int j = 0; j < 4; ++j) xd[j] = xg[j];
#pragma unroll
    for (int j = 0; j < 4; ++j) wd[j] = wg[j];
    __syncthreads();
    for (int c = 0; c < 64; ++c) {
      float4 xv = *(const float4*)(xs + c * 64 + pxq * 4);
      float4 wv = *(const float4*)(wls + c * 64 + mq * 4);
      float xa[4] = {xv.x, xv.y, xv.z, xv.w};
      float wa[4] = {wv.x, wv.y, wv.z, wv.w};
#pragma unroll
      for (int mi = 0; mi < 4; ++mi)
#pragma unroll
        for (int pi = 0; pi < 4; ++pi)
          acc[mi][pi] = fmaf(wa[mi], xa[pi], acc[mi][pi]);
    }
    __syncthreads();
  }

#pragma unroll
  for (int pi = 0; pi < 4; ++pi) {
    float s = 0.f;
#pragma unroll
    for (int mi = 0; mi < 4; ++mi) s += acc[mi][pi] * acc[mi][pi];
    part[(pxq * 4 + pi) * 16 + mq] = s;
  }
  __syncthreads();
  if (tid < 64) {
    float s = 0.f;
#pragma unroll
    for (int k = 0; k < 16; ++k) s += part[tid * 16 + k];
    sinv[tid] = 1.0f / fmaxf(sqrtf(s), 1e-12f);
  }
  __syncthreads();
#pragma unroll
  for (int pi = 0; pi < 4; ++pi) {
    const int px = pxq * 4 + pi;
    const float inv = sinv[px];
    ushort4 v;
    v.x = f2bf(acc[0][pi] * inv);
    v.y = f2bf(acc[1][pi] * inv);
    v.z = f2bf(acc[2][pi] * inv);
    v.w = f2bf(acc[3][pi] * inv);
    *(ushort4*)(qn + (size_t)(pix0 + px) * 64 + mq * 4) = v;
  }
}

// ---------------------------------------------------------------------------
// Kernel 2: per-pixel encoder, streamed-ss + T14 staging order.
// WG = 16 pixels, 256 thr = 4 waves (1 o-tile each, perfectly balanced).
// LDS: ring[2][7 dv][16 px][64 ch] (28,672 B) + o1[25][16][64] (51,200 B)
//      = 79,872 B -> 2 blocks/CU.  o2 (9 pos, 18 KB) reuses ring region.
// conv1 per iter: consume(ir) MFMA -> WRITE(ir+1 from regs) -> ISSUE(ir+2)
//      -> barrier.  cen fragments preloaded once (row-invariant).
// ---------------------------------------------------------------------------
#define ENC_RING 7168              // ushorts per ring slot (7*16*64)
#define ENC_O1   14336             // ushort offset of o1
#define SMEM_ENC 79872             // bytes

__device__ __forceinline__ void store_act(ushort* buf, int pos, int n, int q, int o0,
                                          f32x4 acc, float4 sh) {
  ushort4 v;
  v.x = f2bf(fmaxf(acc[0] + sh.x, 0.0f));
  v.y = f2bf(fmaxf(acc[1] + sh.y, 0.0f));
  v.z = f2bf(fmaxf(acc[2] + sh.z, 0.0f));
  v.w = f2bf(fmaxf(acc[3] + sh.w, 0.0f));
  const int chunk = (o0 >> 3) + (q >> 1);
  *(ushort4*)(buf + (pos * 16 + n) * 64 + ((chunk ^ (n & 7)) * 8) + (q & 1) * 4) = v;
}

__global__ __launch_bounds__(256, 2) void k_encoder(
    const ushort* __restrict__ qn, const ushort* __restrict__ wc_b,
    const float* __restrict__ shift_c, ushort* __restrict__ yout)
{
  extern __shared__ char smem[];
  ushort* enc = (ushort*)smem;        // ring slots at 0 / ENC_RING; o2 later at 0
  ushort* o1 = enc + ENC_O1;

  const int tid = threadIdx.x;
  const int b = blockIdx.z;
  const int tr = blockIdx.y * 4;
  const int tc = blockIdx.x * 4;

  const int lane = tid & 63, wv = tid >> 6;   // 4 waves
  const int n = lane & 15, q = lane >> 4;
  const int o0 = wv * 16;                     // o-tile (16 of 64 out-chan)
  const int sw = n & 7;
  const int rowoff = n * 64;
  const int c0 = ((0 + q) ^ sw) * 8;          // kc=0 chunk offset (ushorts)
  const int c1 = ((4 + q) ^ sw) * 8;          // kc=1 chunk offset

  // ---- ss-row staging units (4 per thread; unit k=3 active for tid<128) ----
  // unit u0 = tid + k*256 (<896): ch=u0&7, px=(u0>>3)&15, dv=u0>>7
  int chk[4], nwk[4], dstk[4], phk[4];
  bool actk[4], nwok[4];
  uint4 cenR[4], nbrR[4];
#pragma unroll
  for (int k = 0; k < 4; ++k) {
    const int u0 = tid + k * 256;
    actk[k] = (u0 < 896);
    const int ch = u0 & 7, px = (u0 >> 3) & 15, dv = (u0 >> 7) & 7;
    chk[k] = ch;
    const int ph = tr + (px >> 2), pw = tc + (px & 3);
    phk[k] = ph;
    nwk[k] = pw + dv - 3;
    nwok[k] = actk[k] && ((unsigned)nwk[k] < 64u);
    dstk[k] = (dv * 16 + px) * 64 + ((ch ^ (px & 7)) * 8);
    cenR[k] = make_uint4(0u, 0u, 0u, 0u);
    if (actk[k])
      cenR[k] = *(const uint4*)(qn + (size_t)((b << 12) + ph * 64 + pw) * 64 + ch * 8);
  }

#define ENC_ISSUE(r)                                                              \
  {                                                                               \
    _Pragma("unroll")                                                             \
    for (int k = 0; k < 4; ++k) {                                                 \
      const int nh = phk[k] + (r) - 3;                                            \
      if (nwok[k] && (unsigned)nh < 64u)                                          \
        nbrR[k] = *(const uint4*)(qn + (size_t)((b << 12) + nh * 64 + nwk[k]) * 64 \
                                  + chk[k] * 8);                                  \
      else                                                                        \
        nbrR[k] = make_uint4(0u, 0u, 0u, 0u);                                     \
    }                                                                             \
  }
#define ENC_WRITE(slot)                                                           \
  {                                                                               \
    _Pragma("unroll")                                                             \
    for (int k = 0; k < 4; ++k) {                                                 \
      if (actk[k]) {                                                              \
        BV8 cv, nv, ov; cv.v = cenR[k]; nv.v = nbrR[k];                           \
        _Pragma("unroll")                                                         \
        for (int j = 0; j < 8; ++j)                                               \
          ov.u[j] = f2bf(fmaxf(bfu(nv.u[j]) * bfu(cv.u[j]), 0.0f));               \
        *(uint4*)((slot) + dstk[k]) = ov.v;                                       \
      }                                                                           \
    }                                                                             \
  }

  // ---- conv1 weight A-fragments (persistent across all 7 rows) ----
  bf16x8 af[18];
#pragma unroll
  for (int t = 0; t < 9; ++t) {
    af[t * 2]     = *(const bf16x8*)(wc_b + (t * 64 + o0 + n) * 64 + q * 8);
    af[t * 2 + 1] = *(const bf16x8*)(wc_b + (t * 64 + o0 + n) * 64 + 32 + q * 8);
  }

  const f32x4 zero = {0.f, 0.f, 0.f, 0.f};
  f32x4 acc[5][5];
#pragma unroll
  for (int u = 0; u < 5; ++u)
#pragma unroll
    for (int v = 0; v < 5; ++v) acc[u][v] = zero;

  // ---- prologue: row 0 into slot 0; row 1 loads in flight ----
  ENC_ISSUE(0);
  ENC_WRITE(enc);
  ENC_ISSUE(1);
  __syncthreads();

  // ---- conv1 main loop ----
#pragma unroll
  for (int ir = 0; ir < 7; ++ir) {
    // consume row ir (slot ir&1)
    {
      const ushort* rowb = enc + (ir & 1) * ENC_RING + rowoff;
      bf16x8 rf0[7], rf1[7];
#pragma unroll
      for (int j = 0; j < 7; ++j) {
        rf0[j] = *(const bf16x8*)(rowb + j * 1024 + c0);
        rf1[j] = *(const bf16x8*)(rowb + j * 1024 + c1);
      }
#pragma unroll
      for (int u = 0; u < 5; ++u) {
        const int du = ir - u;
        if (du >= 0 && du < 3) {
#pragma unroll
          for (int dv = 0; dv < 3; ++dv)
#pragma unroll
            for (int v = 0; v < 5; ++v) {
              acc[u][v] = mfma16(af[(du * 3 + dv) * 2],     rf0[v + dv], acc[u][v]);
              acc[u][v] = mfma16(af[(du * 3 + dv) * 2 + 1], rf1[v + dv], acc[u][v]);
            }
        }
      }
    }
    if (ir < 6) {
      ENC_WRITE(enc + ((ir + 1) & 1) * ENC_RING);   // data arrived pre-barrier
      if (ir < 5) ENC_ISSUE(ir + 2);                // hide under next MFMA
      __syncthreads();
    }
  }

  // ---- conv1 epilogue: BN+relu -> o1 ----
  {
    const float4 sh = *(const float4*)(shift_c + o0 + q * 4);
#pragma unroll
    for (int u = 0; u < 5; ++u)
#pragma unroll
      for (int v = 0; v < 5; ++v)
        store_act(o1, u * 5 + v, n, q, o0, acc[u][v], sh);
  }
  __syncthreads();

  // ---- conv2: 3x3 outputs over 5x5 o1 (2D reuse), o2 -> ring region ----
  {
#pragma unroll
    for (int t = 0; t < 9; ++t) {
      af[t * 2]     = *(const bf16x8*)(wc_b + 9 * 4096 + (t * 64 + o0 + n) * 64 + q * 8);
      af[t * 2 + 1] = *(const bf16x8*)(wc_b + 9 * 4096 + (t * 64 + o0 + n) * 64 + 32 + q * 8);
    }
    f32x4 acc2[3][3];
#pragma unroll
    for (int u = 0; u < 3; ++u)
#pragma unroll
      for (int v = 0; v < 3; ++v) acc2[u][v] = zero;

#pragma unroll
    for (int ir = 0; ir < 5; ++ir) {
      const ushort* rowb = o1 + ir * 5 * 1024 + rowoff;
      bf16x8 rf0[5], rf1[5];
#pragma unroll
      for (int j = 0; j < 5; ++j) {
        rf0[j] = *(const bf16x8*)(rowb + j * 1024 + c0);
        rf1[j] = *(const bf16x8*)(rowb + j * 1024 + c1);
      }
#pragma unroll
      for (int u = 0; u < 3; ++u) {
        const int du = ir - u;
        if (du >= 0 && du < 3) {
#pragma unroll
          for (int dv = 0; dv < 3; ++dv)
#pragma unroll
            for (int v = 0; v < 3; ++v) {
              acc2[u][v] = mfma16(af[(du * 3 + dv) * 2],     rf0[v + dv], acc2[u][v]);
              acc2[u][v] = mfma16(af[(du * 3 + dv) * 2 + 1], rf1[v + dv], acc2[u][v]);
            }
        }
      }
    }
    const float4 sh = *(const float4*)(shift_c + 64 + o0 + q * 4);
#pragma unroll
    for (int u = 0; u < 3; ++u)
#pragma unroll
      for (int v = 0; v < 3; ++v)
        store_act(enc, u * 3 + v, n, q, o0, acc2[u][v], sh);
  }
  __syncthreads();

  // ---- conv3: 1 output over 3x3 o2 -> y (global), all 4 waves ----
  {
#pragma unroll
    for (int t = 0; t < 9; ++t) {
      af[t * 2]     = *(const bf16x8*)(wc_b + 18 * 4096 + (t * 64 + o0 + n) * 64 + q * 8);
      af[t * 2 + 1] = *(const bf16x8*)(wc_b + 18 * 4096 + (t * 64 + o0 + n) * 64 + 32 + q * 8);
    }
    f32x4 a0 = zero, a1 = zero;
#pragma unroll
    for (int tap = 0; tap < 9; ++tap) {
      const ushort* rA = enc + tap * 1024 + rowoff;
      a0 = mfma16(af[tap * 2],     *(const bf16x8*)(rA + c0), a0);
      a1 = mfma16(af[tap * 2 + 1], *(const bf16x8*)(rA + c1), a1);
    }
    f32x4 acc3 = a0 + a1;
    const float4 sh = *(const float4*)(shift_c + 128 + o0 + q * 4);
    ushort4 v;
    v.x = f2bf(fmaxf(acc3[0] + sh.x, 0.0f));
    v.y = f2bf(fmaxf(acc3[1] + sh.y, 0.0f));
    v.z = f2bf(fmaxf(acc3[2] + sh.z, 0.0f));
    v.w = f2bf(fmaxf(acc3[3] + sh.w, 0.0f));
    const int ph = tr + (n >> 2), pw = tc + (n & 3);
    *(ushort4*)(yout + (size_t)((b << 12) + ph * 64 + pw) * 64 + o0 + q * 4) = v;
  }
}

// ---------------------------------------------------------------------------
// Kernel 3: feat = BN(w_out@y); r = x + feat; out = w_f2@relu(w_f1@r+b1)+b2
// WG = 64 pixels (4 n-tiles); 4 waves split 256 output channels.
// Weight A-frags register-cached across the 4 n-tiles.  (R5 shape, verified.)
// ---------------------------------------------------------------------------
#define SMEM_OUT (2 * 64 * 256 * 2)   // rls + hls = 65536 bytes

__global__ __launch_bounds__(256) void k_out(
    const ushort* __restrict__ y, const float* __restrict__ x,
    const ushort* __restrict__ w_out_b, const float* __restrict__ shift_o,
    const ushort* __restrict__ w_f1_b, const float* __restrict__ b_f1,
    const ushort* __restrict__ w_f2_b, const float* __restrict__ b_f2,
    float* __restrict__ out)
{
  extern __shared__ char smem[];
  ushort* rls = (ushort*)smem;                    // [64 px][256 c] swizzled
  ushort* hls = (ushort*)(smem + 64 * 256 * 2);

  const int tid = threadIdx.x, lane = tid & 63, wv = tid >> 6;
  const int n = lane & 15, q = lane >> 4;
  const int pix0 = blockIdx.x * 64;
  const int b = pix0 >> 12, hw0 = pix0 & 4095;
  const int sw = n & 7;
  const f32x4 zero = {0.f, 0.f, 0.f, 0.f};

  // ---- stage A: feat + residual -> r (bf16, LDS, swizzled [px][c]) ----
  {
    bf16x8 wa[8];
#pragma unroll
    for (int mt = 0; mt < 4; ++mt) {
      const int ob = wv * 64 + mt * 16;
      wa[mt * 2]     = *(const bf16x8*)(w_out_b + (ob + n) * 64 + q * 8);
      wa[mt * 2 + 1] = *(const bf16x8*)(w_out_b + (ob + n) * 64 + 32 + q * 8);
    }
    for (int nt = 0; nt < 4; ++nt) {
      const int px0 = nt * 16;
      const bf16x8 yb0 = *(const bf16x8*)(y + (size_t)(pix0 + px0 + n) * 64 + q * 8);
      const bf16x8 yb1 = *(const bf16x8*)(y + (size_t)(pix0 + px0 + n) * 64 + 32 + q * 8);
#pragma unroll
      for (int mt = 0; mt < 4; ++mt) {
        const int ob = wv * 64 + mt * 16;
        f32x4 acc = zero;
        acc = mfma16(wa[mt * 2], yb0, acc);
        acc = mfma16(wa[mt * 2 + 1], yb1, acc);
        const float4 sh = *(const float4*)(shift_o + ob + q * 4);
        const float sha[4] = {sh.x, sh.y, sh.z, sh.w};
        ushort tmp[4];
#pragma unroll
        for (int r = 0; r < 4; ++r) {
          const int o = ob + q * 4 + r;
          const float xv = x[(size_t)(b * 256 + o) * 4096 + hw0 + px0 + n];
          tmp[r] = f2bf(xv + acc[r] + sha[r]);
        }
        ushort4 v; v.x = tmp[0]; v.y = tmp[1]; v.z = tmp[2]; v.w = tmp[3];
        const int chunk = (ob >> 3) + (q >> 1);
        *(ushort4*)(rls + (px0 + n) * 256 + ((chunk ^ sw) * 8) + (q & 1) * 4) = v;
      }
    }
  }
  __syncthreads();

  // ---- stage B: h = relu(w_f1 @ r + b_f1) ----
  {
    bf16x8 wf[32];
#pragma unroll
    for (int mt = 0; mt < 4; ++mt)
#pragma unroll
      for (int kc = 0; kc < 8; ++kc)
        wf[mt * 8 + kc] = *(const bf16x8*)(w_f1_b + (size_t)(wv * 64 + mt * 16 + n) * 256 + kc * 32 + q * 8);
    for (int nt = 0; nt < 4; ++nt) {
      const int px0 = nt * 16;
      bf16x8 rb[8];
#pragma unroll
      for (int kc = 0; kc < 8; ++kc)
        rb[kc] = *(const bf16x8*)(rls + (px0 + n) * 256 + (((kc * 4 + q) ^ sw) * 8));
#pragma unroll
      for (int mt = 0; mt < 4; ++mt) {
        const int ob = wv * 64 + mt * 16;
        f32x4 a0 = zero, a1 = zero;
#pragma unroll
        for (int kc = 0; kc < 8; kc += 2) {
          a0 = mfma16(wf[mt * 8 + kc], rb[kc], a0);
          a1 = mfma16(wf[mt * 8 + kc + 1], rb[kc + 1], a1);
        }
        f32x4 acc = a0 + a1;
        const float4 bb = *(const float4*)(b_f1 + ob + q * 4);
        const float bba[4] = {bb.x, bb.y, bb.z, bb.w};
        ushort tmp[4];
#pragma unroll
        for (int r = 0; r < 4; ++r) tmp[r] = f2bf(fmaxf(acc[r] + bba[r], 0.0f));
        ushort4 v; v.x = tmp[0]; v.y = tmp[1]; v.z = tmp[2]; v.w = tmp[3];
        const int chunk = (ob >> 3) + (q >> 1);
        *(ushort4*)(hls + (px0 + n) * 256 + ((chunk ^ sw) * 8) + (q & 1) * 4) = v;
      }
    }
  }
  __syncthreads();

  // ---- stage C: out = w_f2 @ h + b_f2 (fp32 store) ----
  {
    bf16x8 wf[32];
#pragma unroll
    for (int mt = 0; mt < 4; ++mt)
#pragma unroll
      for (int kc = 0; kc < 8; ++kc)
        wf[mt * 8 + kc] = *(const bf16x8*)(w_f2_b + (size_t)(wv * 64 + mt * 16 + n) * 256 + kc * 32 + q * 8);
    for (int nt = 0; nt < 4; ++nt) {
      const int px0 = nt * 16;
      bf16x8 rb[8];
#pragma unroll
      for (int kc = 0; kc < 8; ++kc)
        rb[kc] = *(const bf16x8*)(hls + (px0 + n) * 256 + (((kc * 4 + q) ^ sw) * 8));
#pragma unroll
      for (int mt = 0; mt < 4; ++mt) {
        const int ob = wv * 64 + mt * 16;
        f32x4 a0 = zero, a1 = zero;
#pragma unroll
        for (int kc = 0; kc < 8; kc += 2) {
          a0 = mfma16(wf[mt * 8 + kc], rb[kc], a0);
          a1 = mfma16(wf[mt * 8 + kc + 1], rb[kc + 1], a1);
        }
        f32x4 acc = a0 + a1;
        const float4 bb = *(const float4*)(b_f2 + ob + q * 4);
        const float bba[4] = {bb.x, bb.y, bb.z, bb.w};
#pragma unroll
        for (int r = 0; r < 4; ++r) {
          const int o = ob + q * 4 + r;
          out[(size_t)(b * 256 + o) * 4096 + hw0 + px0 + n] = acc[r] + bba[r];
        }
      }
    }
  }
}

// ---------------------------------------------------------------------------
extern "C" void kernel_launch(void* const* d_in, const int* in_sizes, int n_in,
                              void* d_out, int out_size, void* d_ws, size_t ws_size,
                              hipStream_t stream) {
  const float* x     = (const float*)d_in[0];
  const float* w_red = (const float*)d_in[1];
  const float* w_c   = (const float*)d_in[2];
  const float* b_c   = (const float*)d_in[3];
  const float* bn_g  = (const float*)d_in[4];
  const float* bn_b  = (const float*)d_in[5];
  const float* bn_m  = (const float*)d_in[6];
  const float* bn_v  = (const float*)d_in[7];
  const float* w_out = (const float*)d_in[8];
  const float* b_out = (const float*)d_in[9];
  const float* bno_g = (const float*)d_in[10];
  const float* bno_b = (const float*)d_in[11];
  const float* bno_m = (const float*)d_in[12];
  const float* bno_v = (const float*)d_in[13];
  const float* w_f1  = (const float*)d_in[14];
  const float* b_f1  = (const float*)d_in[15];
  const float* w_f2  = (const float*)d_in[16];
  const float* b_f2  = (const float*)d_in[17];

  char* ws = (char*)d_ws;
  float*  w_red_t = (float*)(ws + OFF_WRT);
  ushort* wc_b    = (ushort*)(ws + OFF_WCB);
  float*  shift_c = (float*)(ws + OFF_SHC);
  ushort* w_out_b = (ushort*)(ws + OFF_WOB);
  float*  shift_o = (float*)(ws + OFF_SHO);
  ushort* w_f1_b  = (ushort*)(ws + OFF_WF1);
  ushort* w_f2_b  = (ushort*)(ws + OFF_WF2);
  ushort* qnb     = (ushort*)(ws + OFF_QN);
  ushort* yb      = (ushort*)(ws + OFF_Y);

  k_prep<<<1074, 256, 0, stream>>>(w_red, w_c, b_c, bn_g, bn_b, bn_m, bn_v,
                                   w_out, b_out, bno_g, bno_b, bno_m, bno_v,
                                   w_f1, w_f2,
                                   w_red_t, wc_b, shift_c, w_out_b, shift_o, w_f1_b, w_f2_b);
  k_qnorm<<<512, 256, 0, stream>>>(x, w_red_t, qnb);
  k_encoder<<<dim3(16, 16, 8), 256, SMEM_ENC, stream>>>(qnb, wc_b, shift_c, yb);
  k_out<<<512, 256, SMEM_OUT, stream>>>(yb, x, w_out_b, shift_o, w_f1_b, b_f1, w_f2_b, b_f2,
                                        (float*)d_out);
}

// Round 8
// 276.272 us; speedup vs baseline: 1.2870x; 1.2870x over previous
//
#include <hip/hip_runtime.h>
#include <stdint.h>

// ---------------------------------------------------------------------------
// SSM: q=1x1 reduce + L2norm; ss = clamp(unfold7x7 * center); 3x chained 3x3
// conv (+BN+relu) per pixel; 1x1 + BN; residual; FFN (1x1,relu,1x1).
// B=8, C=256, MID=64, H=W=64.  bf16 MFMA 16x16x32 for all heavy GEMMs.
// R8: recombination of verified-best pieces after two over-reach regressions:
//     - encoder: exact R6 (streamed-ss ring, 2 blocks/CU, serial build_row,
//       native f2bf) — 124.8 us verified.  R7's T14 reg-staging spilled
//       (WRITE_SIZE 4->132 MB scratch) and is reverted.
//     - k_out: exact R5 shape (64 px/WG, wf[32] cached) — R6 re-tile
//       regressed via doubled weight traffic.
// (Resubmitted unchanged after GPU-acquisition timeout.)
// ---------------------------------------------------------------------------

typedef __attribute__((ext_vector_type(8))) __bf16 bf16x8;
typedef __attribute__((ext_vector_type(4))) float f32x4;

__device__ __forceinline__ ushort f2bf(float f) {
  __bf16 h = (__bf16)f;                 // RNE, compiler packs pairs
  return __builtin_bit_cast(ushort, h);
}
__device__ __forceinline__ float bfu(ushort h) {
  return __builtin_bit_cast(float, ((uint32_t)h) << 16);
}
__device__ __forceinline__ f32x4 mfma16(bf16x8 a, bf16x8 b, f32x4 c) {
  return __builtin_amdgcn_mfma_f32_16x16x32_bf16(a, b, c, 0, 0, 0);
}

union BV8 { uint4 v; ushort u[8]; };

// ---------------------------------------------------------------------------
// Workspace layout (bytes)
// ---------------------------------------------------------------------------
#define OFF_WRT 0u          // w_red_t  fp32 [256][64]            65536
#define OFF_WCB 65536u      // wc_b     bf16 [3][9][64][64]       221184
#define OFF_SHC 286720u     // shift_c  fp32 [3][64]              768
#define OFF_WOB 287488u     // w_out_b  bf16 [256][64]            32768
#define OFF_SHO 320256u     // shift_o  fp32 [256]                1024
#define OFF_WF1 321280u     // w_f1_b   bf16 [256][256]           131072
#define OFF_WF2 452352u     // w_f2_b   bf16 [256][256]           131072
#define OFF_QN  583424u     // q_n      bf16 [32768][64]          4194304
#define OFF_Y   4777728u    // y        bf16 [32768][64]          4194304

// ---------------------------------------------------------------------------
// Kernel 0: weight prep (fold BN, transpose, cast to bf16)
// ---------------------------------------------------------------------------
__global__ __launch_bounds__(256) void k_prep(
    const float* __restrict__ w_red, const float* __restrict__ w_c, const float* __restrict__ b_c,
    const float* __restrict__ bn_g, const float* __restrict__ bn_b, const float* __restrict__ bn_m,
    const float* __restrict__ bn_v, const float* __restrict__ w_out, const float* __restrict__ b_out,
    const float* __restrict__ bno_g, const float* __restrict__ bno_b, const float* __restrict__ bno_m,
    const float* __restrict__ bno_v, const float* __restrict__ w_f1, const float* __restrict__ w_f2,
    float* __restrict__ w_red_t, ushort* __restrict__ wc_b, float* __restrict__ shift_c,
    ushort* __restrict__ w_out_b, float* __restrict__ shift_o,
    ushort* __restrict__ w_f1_b, ushort* __restrict__ w_f2_b)
{
  int i = blockIdx.x * 256 + threadIdx.x;
  if (i < 16384) {                       // w_red_t[c][mid] = w_red[mid][c]
    int c = i >> 6, m = i & 63;
    w_red_t[i] = w_red[m * 256 + c];
    return;
  }
  i -= 16384;
  if (i < 110592) {                      // wc_b[s][tap][o][c] = w_c[s][o][c][du][dv] * bnscale
    int c = i & 63, o = (i >> 6) & 63, st = i >> 12;
    int tap = st % 9, s = st / 9;
    float sc = bn_g[s * 64 + o] * rsqrtf(bn_v[s * 64 + o] + 1e-5f);
    wc_b[i] = f2bf(w_c[((s * 64 + o) * 64 + c) * 9 + tap] * sc);
    return;
  }
  i -= 110592;
  if (i < 192) {                         // shift_c[s][o]
    int s = i >> 6, o = i & 63;
    float sc = bn_g[s * 64 + o] * rsqrtf(bn_v[s * 64 + o] + 1e-5f);
    shift_c[i] = (b_c[i] - bn_m[i]) * sc + bn_b[i];
    return;
  }
  i -= 192;
  if (i < 16384) {                       // w_out_b[o][c] (bno scale folded)
    int o = i >> 6;
    float sc = bno_g[o] * rsqrtf(bno_v[o] + 1e-5f);
    w_out_b[i] = f2bf(w_out[i] * sc);
    return;
  }
  i -= 16384;
  if (i < 256) {                         // shift_o[o]
    float sc = bno_g[i] * rsqrtf(bno_v[i] + 1e-5f);
    shift_o[i] = (b_out[i] - bno_m[i]) * sc + bno_b[i];
    return;
  }
  i -= 256;
  if (i < 65536) { w_f1_b[i] = f2bf(w_f1[i]); return; }
  i -= 65536;
  if (i < 65536) { w_f2_b[i] = f2bf(w_f2[i]); return; }
}

// ---------------------------------------------------------------------------
// Kernel 1: q = w_red @ x per pixel, L2-normalize over 64 mids -> q_n bf16
// ---------------------------------------------------------------------------
__global__ __launch_bounds__(256) void k_qnorm(
    const float* __restrict__ x, const float* __restrict__ w_red_t, ushort* __restrict__ qn)
{
  __shared__ float xs[64 * 64];     // [c][px]
  __shared__ float wls[64 * 64];    // [c][mid]
  __shared__ float part[64 * 16];   // [px][mq]
  __shared__ float sinv[64];

  const int tid = threadIdx.x;
  const int pix0 = blockIdx.x * 64;
  const int b = pix0 >> 12;
  const int hw0 = pix0 & 4095;
  const int pxq = tid & 15, mq = tid >> 4;
  const int lr = tid >> 2, lseg = tid & 3;

  float acc[4][4] = {};   // [mi][pi]

  for (int c0 = 0; c0 < 256; c0 += 64) {
    const float4* xg = (const float4*)(x + (size_t)(b * 256 + c0 + lr) * 4096 + hw0 + lseg * 16);
    float4* xd = (float4*)(xs + lr * 64 + lseg * 16);
    const float4* wg = (const float4*)(w_red_t + (c0 + lr) * 64 + lseg * 16);
    float4* wd = (float4*)(wls + lr * 64 + lseg * 16);
#pragma unroll
    for (int j = 0; j < 4; ++j) xd[j] = xg[j];
#pragma unroll
    for (int j = 0; j < 4; ++j) wd[j] = wg[j];
    __syncthreads();
    for (int c = 0; c < 64; ++c) {
      float4 xv = *(const float4*)(xs + c * 64 + pxq * 4);
      float4 wv = *(const float4*)(wls + c * 64 + mq * 4);
      float xa[4] = {xv.x, xv.y, xv.z, xv.w};
      float wa[4] = {wv.x, wv.y, wv.z, wv.w};
#pragma unroll
      for (int mi = 0; mi < 4; ++mi)
#pragma unroll
        for (int pi = 0; pi < 4; ++pi)
          acc[mi][pi] = fmaf(wa[mi], xa[pi], acc[mi][pi]);
    }
    __syncthreads();
  }

#pragma unroll
  for (int pi = 0; pi < 4; ++pi) {
    float s = 0.f;
#pragma unroll
    for (int mi = 0; mi < 4; ++mi) s += acc[mi][pi] * acc[mi][pi];
    part[(pxq * 4 + pi) * 16 + mq] = s;
  }
  __syncthreads();
  if (tid < 64) {
    float s = 0.f;
#pragma unroll
    for (int k = 0; k < 16; ++k) s += part[tid * 16 + k];
    sinv[tid] = 1.0f / fmaxf(sqrtf(s), 1e-12f);
  }
  __syncthreads();
#pragma unroll
  for (int pi = 0; pi < 4; ++pi) {
    const int px = pxq * 4 + pi;
    const float inv = sinv[px];
    ushort4 v;
    v.x = f2bf(acc[0][pi] * inv);
    v.y = f2bf(acc[1][pi] * inv);
    v.z = f2bf(acc[2][pi] * inv);
    v.w = f2bf(acc[3][pi] * inv);
    *(ushort4*)(qn + (size_t)(pix0 + px) * 64 + mq * 4) = v;
  }
}

// ---------------------------------------------------------------------------
// Kernel 2: per-pixel encoder, streamed-ss version (R6, verified 124.8 us).
// WG = 16 pixels, 256 thr = 4 waves (1 o-tile each, perfectly balanced).
// LDS: ring[2][7 dv][16 px][64 ch] (28,672 B) + o1[25][16][64] (51,200 B)
//      = 79,872 B -> 2 blocks/CU.  o2 (9 pos, 18 KB) reuses ring region.
// conv1: per ir, build ss row ir+1 (global qn) while consuming row ir (MFMA).
// ---------------------------------------------------------------------------
#define ENC_RING 7168              // ushorts per ring slot (7*16*64)
#define ENC_O1   14336             // ushort offset of o1
#define SMEM_ENC 79872             // bytes

__device__ __forceinline__ void store_act(ushort* buf, int pos, int n, int q, int o0,
                                          f32x4 acc, float4 sh) {
  ushort4 v;
  v.x = f2bf(fmaxf(acc[0] + sh.x, 0.0f));
  v.y = f2bf(fmaxf(acc[1] + sh.y, 0.0f));
  v.z = f2bf(fmaxf(acc[2] + sh.z, 0.0f));
  v.w = f2bf(fmaxf(acc[3] + sh.w, 0.0f));
  const int chunk = (o0 >> 3) + (q >> 1);
  *(ushort4*)(buf + (pos * 16 + n) * 64 + ((chunk ^ (n & 7)) * 8) + (q & 1) * 4) = v;
}

// Build one ss row (7 dv x 16 px x 64 ch) into a ring slot.
// 896 16B-chunk units split over 256 threads (3.5 each).
__device__ __forceinline__ void build_row(
    ushort* dstslot, const ushort* __restrict__ qn,
    int b, int tr, int tc, int ir, int tid)
{
  for (int u0 = tid; u0 < 896; u0 += 256) {
    const int ch = u0 & 7, px = (u0 >> 3) & 15, dv = u0 >> 7;
    const int ph = tr + (px >> 2), pw = tc + (px & 3);
    const int nh = ph + ir - 3, nw = pw + dv - 3;
    uint4 ov4;
    if ((unsigned)nh < 64u && (unsigned)nw < 64u) {
      BV8 cv; cv.v = *(const uint4*)(qn + (size_t)((b << 12) + ph * 64 + pw) * 64 + ch * 8);
      BV8 nv; nv.v = *(const uint4*)(qn + (size_t)((b << 12) + nh * 64 + nw) * 64 + ch * 8);
      BV8 ov;
#pragma unroll
      for (int j = 0; j < 8; ++j)
        ov.u[j] = f2bf(fmaxf(bfu(nv.u[j]) * bfu(cv.u[j]), 0.0f));
      ov4 = ov.v;
    } else {
      ov4 = make_uint4(0u, 0u, 0u, 0u);
    }
    *(uint4*)(dstslot + (dv * 16 + px) * 64 + ((ch ^ (px & 7)) * 8)) = ov4;
  }
}

__global__ __launch_bounds__(256, 2) void k_encoder(
    const ushort* __restrict__ qn, const ushort* __restrict__ wc_b,
    const float* __restrict__ shift_c, ushort* __restrict__ yout)
{
  extern __shared__ char smem[];
  ushort* enc = (ushort*)smem;        // ring slots at 0 / ENC_RING; o2 later at 0
  ushort* o1 = enc + ENC_O1;

  const int tid = threadIdx.x;
  const int b = blockIdx.z;
  const int tr = blockIdx.y * 4;
  const int tc = blockIdx.x * 4;

  const int lane = tid & 63, wv = tid >> 6;   // 4 waves
  const int n = lane & 15, q = lane >> 4;
  const int o0 = wv * 16;                     // o-tile (16 of 64 out-chan)
  const int sw = n & 7;
  const int rowoff = n * 64;
  const int c0 = ((0 + q) ^ sw) * 8;          // kc=0 chunk offset (ushorts)
  const int c1 = ((4 + q) ^ sw) * 8;          // kc=1 chunk offset

  // ---- conv1 weight A-fragments (persistent across all 7 rows) ----
  bf16x8 af[18];
#pragma unroll
  for (int t = 0; t < 9; ++t) {
    af[t * 2]     = *(const bf16x8*)(wc_b + (t * 64 + o0 + n) * 64 + q * 8);
    af[t * 2 + 1] = *(const bf16x8*)(wc_b + (t * 64 + o0 + n) * 64 + 32 + q * 8);
  }

  const f32x4 zero = {0.f, 0.f, 0.f, 0.f};
  f32x4 acc[5][5];
#pragma unroll
  for (int u = 0; u < 5; ++u)
#pragma unroll
    for (int v = 0; v < 5; ++v) acc[u][v] = zero;

  // ---- prologue: build ss row 0 ----
  build_row(enc, qn, b, tr, tc, 0, tid);
  __syncthreads();

  // ---- conv1 main loop: build row ir+1 while consuming row ir ----
#pragma unroll
  for (int ir = 0; ir < 7; ++ir) {
    if (ir < 6)
      build_row(enc + ((ir + 1) & 1) * ENC_RING, qn, b, tr, tc, ir + 1, tid);
    {
      const ushort* rowb = enc + (ir & 1) * ENC_RING + rowoff;
      bf16x8 rf0[7], rf1[7];
#pragma unroll
      for (int j = 0; j < 7; ++j) {
        rf0[j] = *(const bf16x8*)(rowb + j * 1024 + c0);
        rf1[j] = *(const bf16x8*)(rowb + j * 1024 + c1);
      }
#pragma unroll
      for (int u = 0; u < 5; ++u) {
        const int du = ir - u;
        if (du >= 0 && du < 3) {
#pragma unroll
          for (int dv = 0; dv < 3; ++dv)
#pragma unroll
            for (int v = 0; v < 5; ++v) {
              acc[u][v] = mfma16(af[(du * 3 + dv) * 2],     rf0[v + dv], acc[u][v]);
              acc[u][v] = mfma16(af[(du * 3 + dv) * 2 + 1], rf1[v + dv], acc[u][v]);
            }
        }
      }
    }
    if (ir < 6) __syncthreads();
  }

  // ---- conv1 epilogue: BN+relu -> o1 ----
  {
    const float4 sh = *(const float4*)(shift_c + o0 + q * 4);
#pragma unroll
    for (int u = 0; u < 5; ++u)
#pragma unroll
      for (int v = 0; v < 5; ++v)
        store_act(o1, u * 5 + v, n, q, o0, acc[u][v], sh);
  }
  __syncthreads();

  // ---- conv2: 3x3 outputs over 5x5 o1 (2D reuse), o2 -> ring region ----
  {
#pragma unroll
    for (int t = 0; t < 9; ++t) {
      af[t * 2]     = *(const bf16x8*)(wc_b + 9 * 4096 + (t * 64 + o0 + n) * 64 + q * 8);
      af[t * 2 + 1] = *(const bf16x8*)(wc_b + 9 * 4096 + (t * 64 + o0 + n) * 64 + 32 + q * 8);
    }
    f32x4 acc2[3][3];
#pragma unroll
    for (int u = 0; u < 3; ++u)
#pragma unroll
      for (int v = 0; v < 3; ++v) acc2[u][v] = zero;

#pragma unroll
    for (int ir = 0; ir < 5; ++ir) {
      const ushort* rowb = o1 + ir * 5 * 1024 + rowoff;
      bf16x8 rf0[5], rf1[5];
#pragma unroll
      for (int j = 0; j < 5; ++j) {
        rf0[j] = *(const bf16x8*)(rowb + j * 1024 + c0);
        rf1[j] = *(const bf16x8*)(rowb + j * 1024 + c1);
      }
#pragma unroll
      for (int u = 0; u < 3; ++u) {
        const int du = ir - u;
        if (du >= 0 && du < 3) {
#pragma unroll
          for (int dv = 0; dv < 3; ++dv)
#pragma unroll
            for (int v = 0; v < 3; ++v) {
              acc2[u][v] = mfma16(af[(du * 3 + dv) * 2],     rf0[v + dv], acc2[u][v]);
              acc2[u][v] = mfma16(af[(du * 3 + dv) * 2 + 1], rf1[v + dv], acc2[u][v]);
            }
        }
      }
    }
    const float4 sh = *(const float4*)(shift_c + 64 + o0 + q * 4);
#pragma unroll
    for (int u = 0; u < 3; ++u)
#pragma unroll
      for (int v = 0; v < 3; ++v)
        store_act(enc, u * 3 + v, n, q, o0, acc2[u][v], sh);
  }
  __syncthreads();

  // ---- conv3: 1 output over 3x3 o2 -> y (global), all 4 waves ----
  {
#pragma unroll
    for (int t = 0; t < 9; ++t) {
      af[t * 2]     = *(const bf16x8*)(wc_b + 18 * 4096 + (t * 64 + o0 + n) * 64 + q * 8);
      af[t * 2 + 1] = *(const bf16x8*)(wc_b + 18 * 4096 + (t * 64 + o0 + n) * 64 + 32 + q * 8);
    }
    f32x4 a0 = zero, a1 = zero;
#pragma unroll
    for (int tap = 0; tap < 9; ++tap) {
      const ushort* rA = enc + tap * 1024 + rowoff;
      a0 = mfma16(af[tap * 2],     *(const bf16x8*)(rA + c0), a0);
      a1 = mfma16(af[tap * 2 + 1], *(const bf16x8*)(rA + c1), a1);
    }
    f32x4 acc3 = a0 + a1;
    const float4 sh = *(const float4*)(shift_c + 128 + o0 + q * 4);
    ushort4 v;
    v.x = f2bf(fmaxf(acc3[0] + sh.x, 0.0f));
    v.y = f2bf(fmaxf(acc3[1] + sh.y, 0.0f));
    v.z = f2bf(fmaxf(acc3[2] + sh.z, 0.0f));
    v.w = f2bf(fmaxf(acc3[3] + sh.w, 0.0f));
    const int ph = tr + (n >> 2), pw = tc + (n & 3);
    *(ushort4*)(yout + (size_t)((b << 12) + ph * 64 + pw) * 64 + o0 + q * 4) = v;
  }
}

// ---------------------------------------------------------------------------
// Kernel 3: feat = BN(w_out@y); r = x + feat; out = w_f2@relu(w_f1@r+b1)+b2
// WG = 64 pixels (4 n-tiles); 4 waves split 256 output channels.
// Weight A-frags register-cached across the 4 n-tiles.  (R5 shape, verified.)
// ---------------------------------------------------------------------------
#define SMEM_OUT (2 * 64 * 256 * 2)   // rls + hls = 65536 bytes

__global__ __launch_bounds__(256) void k_out(
    const ushort* __restrict__ y, const float* __restrict__ x,
    const ushort* __restrict__ w_out_b, const float* __restrict__ shift_o,
    const ushort* __restrict__ w_f1_b, const float* __restrict__ b_f1,
    const ushort* __restrict__ w_f2_b, const float* __restrict__ b_f2,
    float* __restrict__ out)
{
  extern __shared__ char smem[];
  ushort* rls = (ushort*)smem;                    // [64 px][256 c] swizzled
  ushort* hls = (ushort*)(smem + 64 * 256 * 2);

  const int tid = threadIdx.x, lane = tid & 63, wv = tid >> 6;
  const int n = lane & 15, q = lane >> 4;
  const int pix0 = blockIdx.x * 64;
  const int b = pix0 >> 12, hw0 = pix0 & 4095;
  const int sw = n & 7;
  const f32x4 zero = {0.f, 0.f, 0.f, 0.f};

  // ---- stage A: feat + residual -> r (bf16, LDS, swizzled [px][c]) ----
  {
    bf16x8 wa[8];
#pragma unroll
    for (int mt = 0; mt < 4; ++mt) {
      const int ob = wv * 64 + mt * 16;
      wa[mt * 2]     = *(const bf16x8*)(w_out_b + (ob + n) * 64 + q * 8);
      wa[mt * 2 + 1] = *(const bf16x8*)(w_out_b + (ob + n) * 64 + 32 + q * 8);
    }
    for (int nt = 0; nt < 4; ++nt) {
      const int px0 = nt * 16;
      const bf16x8 yb0 = *(const bf16x8*)(y + (size_t)(pix0 + px0 + n) * 64 + q * 8);
      const bf16x8 yb1 = *(const bf16x8*)(y + (size_t)(pix0 + px0 + n) * 64 + 32 + q * 8);
#pragma unroll
      for (int mt = 0; mt < 4; ++mt) {
        const int ob = wv * 64 + mt * 16;
        f32x4 acc = zero;
        acc = mfma16(wa[mt * 2], yb0, acc);
        acc = mfma16(wa[mt * 2 + 1], yb1, acc);
        const float4 sh = *(const float4*)(shift_o + ob + q * 4);
        const float sha[4] = {sh.x, sh.y, sh.z, sh.w};
        ushort tmp[4];
#pragma unroll
        for (int r = 0; r < 4; ++r) {
          const int o = ob + q * 4 + r;
          const float xv = x[(size_t)(b * 256 + o) * 4096 + hw0 + px0 + n];
          tmp[r] = f2bf(xv + acc[r] + sha[r]);
        }
        ushort4 v; v.x = tmp[0]; v.y = tmp[1]; v.z = tmp[2]; v.w = tmp[3];
        const int chunk = (ob >> 3) + (q >> 1);
        *(ushort4*)(rls + (px0 + n) * 256 + ((chunk ^ sw) * 8) + (q & 1) * 4) = v;
      }
    }
  }
  __syncthreads();

  // ---- stage B: h = relu(w_f1 @ r + b_f1) ----
  {
    bf16x8 wf[32];
#pragma unroll
    for (int mt = 0; mt < 4; ++mt)
#pragma unroll
      for (int kc = 0; kc < 8; ++kc)
        wf[mt * 8 + kc] = *(const bf16x8*)(w_f1_b + (size_t)(wv * 64 + mt * 16 + n) * 256 + kc * 32 + q * 8);
    for (int nt = 0; nt < 4; ++nt) {
      const int px0 = nt * 16;
      bf16x8 rb[8];
#pragma unroll
      for (int kc = 0; kc < 8; ++kc)
        rb[kc] = *(const bf16x8*)(rls + (px0 + n) * 256 + (((kc * 4 + q) ^ sw) * 8));
#pragma unroll
      for (int mt = 0; mt < 4; ++mt) {
        const int ob = wv * 64 + mt * 16;
        f32x4 a0 = zero, a1 = zero;
#pragma unroll
        for (int kc = 0; kc < 8; kc += 2) {
          a0 = mfma16(wf[mt * 8 + kc], rb[kc], a0);
          a1 = mfma16(wf[mt * 8 + kc + 1], rb[kc + 1], a1);
        }
        f32x4 acc = a0 + a1;
        const float4 bb = *(const float4*)(b_f1 + ob + q * 4);
        const float bba[4] = {bb.x, bb.y, bb.z, bb.w};
        ushort tmp[4];
#pragma unroll
        for (int r = 0; r < 4; ++r) tmp[r] = f2bf(fmaxf(acc[r] + bba[r], 0.0f));
        ushort4 v; v.x = tmp[0]; v.y = tmp[1]; v.z = tmp[2]; v.w = tmp[3];
        const int chunk = (ob >> 3) + (q >> 1);
        *(ushort4*)(hls + (px0 + n) * 256 + ((chunk ^ sw) * 8) + (q & 1) * 4) = v;
      }
    }
  }
  __syncthreads();

  // ---- stage C: out = w_f2 @ h + b_f2 (fp32 store) ----
  {
    bf16x8 wf[32];
#pragma unroll
    for (int mt = 0; mt < 4; ++mt)
#pragma unroll
      for (int kc = 0; kc < 8; ++kc)
        wf[mt * 8 + kc] = *(const bf16x8*)(w_f2_b + (size_t)(wv * 64 + mt * 16 + n) * 256 + kc * 32 + q * 8);
    for (int nt = 0; nt < 4; ++nt) {
      const int px0 = nt * 16;
      bf16x8 rb[8];
#pragma unroll
      for (int kc = 0; kc < 8; ++kc)
        rb[kc] = *(const bf16x8*)(hls + (px0 + n) * 256 + (((kc * 4 + q) ^ sw) * 8));
#pragma unroll
      for (int mt = 0; mt < 4; ++mt) {
        const int ob = wv * 64 + mt * 16;
        f32x4 a0 = zero, a1 = zero;
#pragma unroll
        for (int kc = 0; kc < 8; kc += 2) {
          a0 = mfma16(wf[mt * 8 + kc], rb[kc], a0);
          a1 = mfma16(wf[mt * 8 + kc + 1], rb[kc + 1], a1);
        }
        f32x4 acc = a0 + a1;
        const float4 bb = *(const float4*)(b_f2 + ob + q * 4);
        const float bba[4] = {bb.x, bb.y, bb.z, bb.w};
#pragma unroll
        for (int r = 0; r < 4; ++r) {
          const int o = ob + q * 4 + r;
          out[(size_t)(b * 256 + o) * 4096 + hw0 + px0 + n] = acc[r] + bba[r];
        }
      }
    }
  }
}

// ---------------------------------------------------------------------------
extern "C" void kernel_launch(void* const* d_in, const int* in_sizes, int n_in,
                              void* d_out, int out_size, void* d_ws, size_t ws_size,
                              hipStream_t stream) {
  const float* x     = (const float*)d_in[0];
  const float* w_red = (const float*)d_in[1];
  const float* w_c   = (const float*)d_in[2];
  const float* b_c   = (const float*)d_in[3];
  const float* bn_g  = (const float*)d_in[4];
  const float* bn_b  = (const float*)d_in[5];
  const float* bn_m  = (const float*)d_in[6];
  const float* bn_v  = (const float*)d_in[7];
  const float* w_out = (const float*)d_in[8];
  const float* b_out = (const float*)d_in[9];
  const float* bno_g = (const float*)d_in[10];
  const float* bno_b = (const float*)d_in[11];
  const float* bno_m = (const float*)d_in[12];
  const float* bno_v = (const float*)d_in[13];
  const float* w_f1  = (const float*)d_in[14];
  const float* b_f1  = (const float*)d_in[15];
  const float* w_f2  = (const float*)d_in[16];
  const float* b_f2  = (const float*)d_in[17];

  char* ws = (char*)d_ws;
  float*  w_red_t = (float*)(ws + OFF_WRT);
  ushort* wc_b    = (ushort*)(ws + OFF_WCB);
  float*  shift_c = (float*)(ws + OFF_SHC);
  ushort* w_out_b = (ushort*)(ws + OFF_WOB);
  float*  shift_o = (float*)(ws + OFF_SHO);
  ushort* w_f1_b  = (ushort*)(ws + OFF_WF1);
  ushort* w_f2_b  = (ushort*)(ws + OFF_WF2);
  ushort* qnb     = (ushort*)(ws + OFF_QN);
  ushort* yb      = (ushort*)(ws + OFF_Y);

  k_prep<<<1074, 256, 0, stream>>>(w_red, w_c, b_c, bn_g, bn_b, bn_m, bn_v,
                                   w_out, b_out, bno_g, bno_b, bno_m, bno_v,
                                   w_f1, w_f2,
                                   w_red_t, wc_b, shift_c, w_out_b, shift_o, w_f1_b, w_f2_b);
  k_qnorm<<<512, 256, 0, stream>>>(x, w_red_t, qnb);
  k_encoder<<<dim3(16, 16, 8), 256, SMEM_ENC, stream>>>(qnb, wc_b, shift_c, yb);
  k_out<<<512, 256, SMEM_OUT, stream>>>(yb, x, w_out_b, shift_o, w_f1_b, b_f1, w_f2_b, b_f2,
                                        (float*)d_out);
}

// Round 13
// 276.060 us; speedup vs baseline: 1.2880x; 1.0008x over previous
//
#include <hip/hip_runtime.h>
#include <stdint.h>

// ---------------------------------------------------------------------------
// SSM: q=1x1 reduce + L2norm; ss = clamp(unfold7x7 * center); 3x chained 3x3
// conv (+BN+relu) per pixel; 1x1 + BN; residual; FFN (1x1,relu,1x1).
// B=8, C=256, MID=64, H=W=64.  bf16 MFMA 16x16x32 for all heavy GEMMs.
// R9: k_qnorm rewritten as MFMA GEMM with split-bf16 precision recovery
//     (q = Wh@xh + Wh@xl + Wl@xh, err ~2^-16 << bf16 storage of qn).
//     Replaces 4096 scalar FMA + 512 LDS reads + 16-way-conflicted staging
//     per thread with 96 MFMA + direct-from-global fragments, no LDS.
//     w pre-split in k_prep to w_hi/w_lo[64][256] bf16 (reuses w_red_t slot).
// R8 verified: encoder 124.7 us (streamed-ss ring), k_out R5 shape.
// (Resubmitted unchanged after repeated GPU-acquisition timeouts.)
// ---------------------------------------------------------------------------

typedef __attribute__((ext_vector_type(8))) __bf16 bf16x8;
typedef __attribute__((ext_vector_type(4))) float f32x4;

__device__ __forceinline__ ushort f2bf(float f) {
  __bf16 h = (__bf16)f;                 // RNE, compiler packs pairs
  return __builtin_bit_cast(ushort, h);
}
__device__ __forceinline__ float bfu(ushort h) {
  return __builtin_bit_cast(float, ((uint32_t)h) << 16);
}
__device__ __forceinline__ f32x4 mfma16(bf16x8 a, bf16x8 b, f32x4 c) {
  return __builtin_amdgcn_mfma_f32_16x16x32_bf16(a, b, c, 0, 0, 0);
}

union BV8 { uint4 v; ushort u[8]; };
union BW8 { bf16x8 v; ushort u[8]; };

// ---------------------------------------------------------------------------
// Workspace layout (bytes)
// ---------------------------------------------------------------------------
#define OFF_WHI 0u          // w_hi     bf16 [64][256]            32768
#define OFF_WLO 32768u      // w_lo     bf16 [64][256]            32768
#define OFF_WCB 65536u      // wc_b     bf16 [3][9][64][64]       221184
#define OFF_SHC 286720u     // shift_c  fp32 [3][64]              768
#define OFF_WOB 287488u     // w_out_b  bf16 [256][64]            32768
#define OFF_SHO 320256u     // shift_o  fp32 [256]                1024
#define OFF_WF1 321280u     // w_f1_b   bf16 [256][256]           131072
#define OFF_WF2 452352u     // w_f2_b   bf16 [256][256]           131072
#define OFF_QN  583424u     // q_n      bf16 [32768][64]          4194304
#define OFF_Y   4777728u    // y        bf16 [32768][64]          4194304

// ---------------------------------------------------------------------------
// Kernel 0: weight prep (fold BN, transpose/split, cast to bf16)
// ---------------------------------------------------------------------------
__global__ __launch_bounds__(256) void k_prep(
    const float* __restrict__ w_red, const float* __restrict__ w_c, const float* __restrict__ b_c,
    const float* __restrict__ bn_g, const float* __restrict__ bn_b, const float* __restrict__ bn_m,
    const float* __restrict__ bn_v, const float* __restrict__ w_out, const float* __restrict__ b_out,
    const float* __restrict__ bno_g, const float* __restrict__ bno_b, const float* __restrict__ bno_m,
    const float* __restrict__ bno_v, const float* __restrict__ w_f1, const float* __restrict__ w_f2,
    ushort* __restrict__ w_hi, ushort* __restrict__ w_lo,
    ushort* __restrict__ wc_b, float* __restrict__ shift_c,
    ushort* __restrict__ w_out_b, float* __restrict__ shift_o,
    ushort* __restrict__ w_f1_b, ushort* __restrict__ w_f2_b)
{
  int i = blockIdx.x * 256 + threadIdx.x;
  if (i < 16384) {                       // split w_red[mid][c] -> hi/lo bf16
    float w = w_red[i];                  // i = mid*256 + c (row-major already)
    ushort h = f2bf(w);
    w_hi[i] = h;
    w_lo[i] = f2bf(w - bfu(h));
    return;
  }
  i -= 16384;
  if (i < 110592) {                      // wc_b[s][tap][o][c] = w_c[s][o][c][du][dv] * bnscale
    int c = i & 63, o = (i >> 6) & 63, st = i >> 12;
    int tap = st % 9, s = st / 9;
    float sc = bn_g[s * 64 + o] * rsqrtf(bn_v[s * 64 + o] + 1e-5f);
    wc_b[i] = f2bf(w_c[((s * 64 + o) * 64 + c) * 9 + tap] * sc);
    return;
  }
  i -= 110592;
  if (i < 192) {                         // shift_c[s][o]
    int s = i >> 6, o = i & 63;
    float sc = bn_g[s * 64 + o] * rsqrtf(bn_v[s * 64 + o] + 1e-5f);
    shift_c[i] = (b_c[i] - bn_m[i]) * sc + bn_b[i];
    return;
  }
  i -= 192;
  if (i < 16384) {                       // w_out_b[o][c] (bno scale folded)
    int o = i >> 6;
    float sc = bno_g[o] * rsqrtf(bno_v[o] + 1e-5f);
    w_out_b[i] = f2bf(w_out[i] * sc);
    return;
  }
  i -= 16384;
  if (i < 256) {                         // shift_o[o]
    float sc = bno_g[i] * rsqrtf(bno_v[i] + 1e-5f);
    shift_o[i] = (b_out[i] - bno_m[i]) * sc + bno_b[i];
    return;
  }
  i -= 256;
  if (i < 65536) { w_f1_b[i] = f2bf(w_f1[i]); return; }
  i -= 65536;
  if (i < 65536) { w_f2_b[i] = f2bf(w_f2[i]); return; }
}

// ---------------------------------------------------------------------------
// Kernel 1 (R9): q = w_red @ x per pixel via MFMA, split-bf16 precision.
// WG = 64 px, 4 waves x 16 px.  Wave: C[64 mid][16 px] via 4 mid-tiles.
// x fragments loaded straight from global (64B segments), no LDS/barriers.
// L2-norm: lane group {n, n+16, n+32, n+48} holds all 64 mids of px=n.
// ---------------------------------------------------------------------------
__global__ __launch_bounds__(256) void k_qnorm(
    const float* __restrict__ x, const ushort* __restrict__ w_hi,
    const ushort* __restrict__ w_lo, ushort* __restrict__ qn)
{
  const int tid = threadIdx.x, lane = tid & 63, wv = tid >> 6;
  const int n = lane & 15, q = lane >> 4;
  const int pix0 = blockIdx.x * 64;
  const int b = pix0 >> 12, hw0 = pix0 & 4095;
  const int pxg = hw0 + wv * 16 + n;          // pixel within batch image
  const float* xb = x + (size_t)b * 256 * 4096 + pxg;

  const f32x4 zero = {0.f, 0.f, 0.f, 0.f};
  f32x4 acc[4] = {zero, zero, zero, zero};    // [mt] -> mids mt*16 + q*4 + r

#pragma unroll
  for (int kk = 0; kk < 8; ++kk) {
    const int cbase = kk * 32 + q * 8;        // 8 consecutive input channels
    float xv[8];
#pragma unroll
    for (int j = 0; j < 8; ++j)
      xv[j] = xb[(size_t)(cbase + j) * 4096];
    BW8 xh, xl;
#pragma unroll
    for (int j = 0; j < 8; ++j) {
      const ushort h = f2bf(xv[j]);           // hi = RNE bf16
      xh.u[j] = h;
      xl.u[j] = f2bf(xv[j] - bfu(h));         // lo = exact fp32 residual
    }
#pragma unroll
    for (int mt = 0; mt < 4; ++mt) {
      const bf16x8 wh = *(const bf16x8*)(w_hi + (mt * 16 + n) * 256 + cbase);
      const bf16x8 wl = *(const bf16x8*)(w_lo + (mt * 16 + n) * 256 + cbase);
      acc[mt] = mfma16(wh, xh.v, acc[mt]);
      acc[mt] = mfma16(wh, xl.v, acc[mt]);
      acc[mt] = mfma16(wl, xh.v, acc[mt]);
    }
  }

  // ---- L2 norm over 64 mids for px = n (lanes n, n^16, n^32 hold the rest)
  float s = 0.f;
#pragma unroll
  for (int mt = 0; mt < 4; ++mt)
#pragma unroll
    for (int r = 0; r < 4; ++r) s += acc[mt][r] * acc[mt][r];
  s += __shfl_xor(s, 16);
  s += __shfl_xor(s, 32);
  const float inv = 1.0f / fmaxf(sqrtf(s), 1e-12f);

#pragma unroll
  for (int mt = 0; mt < 4; ++mt) {
    ushort4 v;
    v.x = f2bf(acc[mt][0] * inv);
    v.y = f2bf(acc[mt][1] * inv);
    v.z = f2bf(acc[mt][2] * inv);
    v.w = f2bf(acc[mt][3] * inv);
    *(ushort4*)(qn + (size_t)(pix0 + wv * 16 + n) * 64 + mt * 16 + q * 4) = v;
  }
}

// ---------------------------------------------------------------------------
// Kernel 2: per-pixel encoder, streamed-ss version (R6/R8, verified 124.7 us).
// WG = 16 pixels, 256 thr = 4 waves (1 o-tile each, perfectly balanced).
// LDS: ring[2][7 dv][16 px][64 ch] (28,672 B) + o1[25][16][64] (51,200 B)
//      = 79,872 B -> 2 blocks/CU.  o2 (9 pos, 18 KB) reuses ring region.
// conv1: per ir, build ss row ir+1 (global qn) while consuming row ir (MFMA).
// ---------------------------------------------------------------------------
#define ENC_RING 7168              // ushorts per ring slot (7*16*64)
#define ENC_O1   14336             // ushort offset of o1
#define SMEM_ENC 79872             // bytes

__device__ __forceinline__ void store_act(ushort* buf, int pos, int n, int q, int o0,
                                          f32x4 acc, float4 sh) {
  ushort4 v;
  v.x = f2bf(fmaxf(acc[0] + sh.x, 0.0f));
  v.y = f2bf(fmaxf(acc[1] + sh.y, 0.0f));
  v.z = f2bf(fmaxf(acc[2] + sh.z, 0.0f));
  v.w = f2bf(fmaxf(acc[3] + sh.w, 0.0f));
  const int chunk = (o0 >> 3) + (q >> 1);
  *(ushort4*)(buf + (pos * 16 + n) * 64 + ((chunk ^ (n & 7)) * 8) + (q & 1) * 4) = v;
}

// Build one ss row (7 dv x 16 px x 64 ch) into a ring slot.
// 896 16B-chunk units split over 256 threads (3.5 each).
__device__ __forceinline__ void build_row(
    ushort* dstslot, const ushort* __restrict__ qn,
    int b, int tr, int tc, int ir, int tid)
{
  for (int u0 = tid; u0 < 896; u0 += 256) {
    const int ch = u0 & 7, px = (u0 >> 3) & 15, dv = u0 >> 7;
    const int ph = tr + (px >> 2), pw = tc + (px & 3);
    const int nh = ph + ir - 3, nw = pw + dv - 3;
    uint4 ov4;
    if ((unsigned)nh < 64u && (unsigned)nw < 64u) {
      BV8 cv; cv.v = *(const uint4*)(qn + (size_t)((b << 12) + ph * 64 + pw) * 64 + ch * 8);
      BV8 nv; nv.v = *(const uint4*)(qn + (size_t)((b << 12) + nh * 64 + nw) * 64 + ch * 8);
      BV8 ov;
#pragma unroll
      for (int j = 0; j < 8; ++j)
        ov.u[j] = f2bf(fmaxf(bfu(nv.u[j]) * bfu(cv.u[j]), 0.0f));
      ov4 = ov.v;
    } else {
      ov4 = make_uint4(0u, 0u, 0u, 0u);
    }
    *(uint4*)(dstslot + (dv * 16 + px) * 64 + ((ch ^ (px & 7)) * 8)) = ov4;
  }
}

__global__ __launch_bounds__(256, 2) void k_encoder(
    const ushort* __restrict__ qn, const ushort* __restrict__ wc_b,
    const float* __restrict__ shift_c, ushort* __restrict__ yout)
{
  extern __shared__ char smem[];
  ushort* enc = (ushort*)smem;        // ring slots at 0 / ENC_RING; o2 later at 0
  ushort* o1 = enc + ENC_O1;

  const int tid = threadIdx.x;
  const int b = blockIdx.z;
  const int tr = blockIdx.y * 4;
  const int tc = blockIdx.x * 4;

  const int lane = tid & 63, wv = tid >> 6;   // 4 waves
  const int n = lane & 15, q = lane >> 4;
  const int o0 = wv * 16;                     // o-tile (16 of 64 out-chan)
  const int sw = n & 7;
  const int rowoff = n * 64;
  const int c0 = ((0 + q) ^ sw) * 8;          // kc=0 chunk offset (ushorts)
  const int c1 = ((4 + q) ^ sw) * 8;          // kc=1 chunk offset

  // ---- conv1 weight A-fragments (persistent across all 7 rows) ----
  bf16x8 af[18];
#pragma unroll
  for (int t = 0; t < 9; ++t) {
    af[t * 2]     = *(const bf16x8*)(wc_b + (t * 64 + o0 + n) * 64 + q * 8);
    af[t * 2 + 1] = *(const bf16x8*)(wc_b + (t * 64 + o0 + n) * 64 + 32 + q * 8);
  }

  const f32x4 zero = {0.f, 0.f, 0.f, 0.f};
  f32x4 acc[5][5];
#pragma unroll
  for (int u = 0; u < 5; ++u)
#pragma unroll
    for (int v = 0; v < 5; ++v) acc[u][v] = zero;

  // ---- prologue: build ss row 0 ----
  build_row(enc, qn, b, tr, tc, 0, tid);
  __syncthreads();

  // ---- conv1 main loop: build row ir+1 while consuming row ir ----
#pragma unroll
  for (int ir = 0; ir < 7; ++ir) {
    if (ir < 6)
      build_row(enc + ((ir + 1) & 1) * ENC_RING, qn, b, tr, tc, ir + 1, tid);
    {
      const ushort* rowb = enc + (ir & 1) * ENC_RING + rowoff;
      bf16x8 rf0[7], rf1[7];
#pragma unroll
      for (int j = 0; j < 7; ++j) {
        rf0[j] = *(const bf16x8*)(rowb + j * 1024 + c0);
        rf1[j] = *(const bf16x8*)(rowb + j * 1024 + c1);
      }
#pragma unroll
      for (int u = 0; u < 5; ++u) {
        const int du = ir - u;
        if (du >= 0 && du < 3) {
#pragma unroll
          for (int dv = 0; dv < 3; ++dv)
#pragma unroll
            for (int v = 0; v < 5; ++v) {
              acc[u][v] = mfma16(af[(du * 3 + dv) * 2],     rf0[v + dv], acc[u][v]);
              acc[u][v] = mfma16(af[(du * 3 + dv) * 2 + 1], rf1[v + dv], acc[u][v]);
            }
        }
      }
    }
    if (ir < 6) __syncthreads();
  }

  // ---- conv1 epilogue: BN+relu -> o1 ----
  {
    const float4 sh = *(const float4*)(shift_c + o0 + q * 4);
#pragma unroll
    for (int u = 0; u < 5; ++u)
#pragma unroll
      for (int v = 0; v < 5; ++v)
        store_act(o1, u * 5 + v, n, q, o0, acc[u][v], sh);
  }
  __syncthreads();

  // ---- conv2: 3x3 outputs over 5x5 o1 (2D reuse), o2 -> ring region ----
  {
#pragma unroll
    for (int t = 0; t < 9; ++t) {
      af[t * 2]     = *(const bf16x8*)(wc_b + 9 * 4096 + (t * 64 + o0 + n) * 64 + q * 8);
      af[t * 2 + 1] = *(const bf16x8*)(wc_b + 9 * 4096 + (t * 64 + o0 + n) * 64 + 32 + q * 8);
    }
    f32x4 acc2[3][3];
#pragma unroll
    for (int u = 0; u < 3; ++u)
#pragma unroll
      for (int v = 0; v < 3; ++v) acc2[u][v] = zero;

#pragma unroll
    for (int ir = 0; ir < 5; ++ir) {
      const ushort* rowb = o1 + ir * 5 * 1024 + rowoff;
      bf16x8 rf0[5], rf1[5];
#pragma unroll
      for (int j = 0; j < 5; ++j) {
        rf0[j] = *(const bf16x8*)(rowb + j * 1024 + c0);
        rf1[j] = *(const bf16x8*)(rowb + j * 1024 + c1);
      }
#pragma unroll
      for (int u = 0; u < 3; ++u) {
        const int du = ir - u;
        if (du >= 0 && du < 3) {
#pragma unroll
          for (int dv = 0; dv < 3; ++dv)
#pragma unroll
            for (int v = 0; v < 3; ++v) {
              acc2[u][v] = mfma16(af[(du * 3 + dv) * 2],     rf0[v + dv], acc2[u][v]);
              acc2[u][v] = mfma16(af[(du * 3 + dv) * 2 + 1], rf1[v + dv], acc2[u][v]);
            }
        }
      }
    }
    const float4 sh = *(const float4*)(shift_c + 64 + o0 + q * 4);
#pragma unroll
    for (int u = 0; u < 3; ++u)
#pragma unroll
      for (int v = 0; v < 3; ++v)
        store_act(enc, u * 3 + v, n, q, o0, acc2[u][v], sh);
  }
  __syncthreads();

  // ---- conv3: 1 output over 3x3 o2 -> y (global), all 4 waves ----
  {
#pragma unroll
    for (int t = 0; t < 9; ++t) {
      af[t * 2]     = *(const bf16x8*)(wc_b + 18 * 4096 + (t * 64 + o0 + n) * 64 + q * 8);
      af[t * 2 + 1] = *(const bf16x8*)(wc_b + 18 * 4096 + (t * 64 + o0 + n) * 64 + 32 + q * 8);
    }
    f32x4 a0 = zero, a1 = zero;
#pragma unroll
    for (int tap = 0; tap < 9; ++tap) {
      const ushort* rA = enc + tap * 1024 + rowoff;
      a0 = mfma16(af[tap * 2],     *(const bf16x8*)(rA + c0), a0);
      a1 = mfma16(af[tap * 2 + 1], *(const bf16x8*)(rA + c1), a1);
    }
    f32x4 acc3 = a0 + a1;
    const float4 sh = *(const float4*)(shift_c + 128 + o0 + q * 4);
    ushort4 v;
    v.x = f2bf(fmaxf(acc3[0] + sh.x, 0.0f));
    v.y = f2bf(fmaxf(acc3[1] + sh.y, 0.0f));
    v.z = f2bf(fmaxf(acc3[2] + sh.z, 0.0f));
    v.w = f2bf(fmaxf(acc3[3] + sh.w, 0.0f));
    const int ph = tr + (n >> 2), pw = tc + (n & 3);
    *(ushort4*)(yout + (size_t)((b << 12) + ph * 64 + pw) * 64 + o0 + q * 4) = v;
  }
}

// ---------------------------------------------------------------------------
// Kernel 3: feat = BN(w_out@y); r = x + feat; out = w_f2@relu(w_f1@r+b1)+b2
// WG = 64 pixels (4 n-tiles); 4 waves split 256 output channels.
// Weight A-frags register-cached across the 4 n-tiles.  (R5 shape, verified.)
// ---------------------------------------------------------------------------
#define SMEM_OUT (2 * 64 * 256 * 2)   // rls + hls = 65536 bytes

__global__ __launch_bounds__(256) void k_out(
    const ushort* __restrict__ y, const float* __restrict__ x,
    const ushort* __restrict__ w_out_b, const float* __restrict__ shift_o,
    const ushort* __restrict__ w_f1_b, const float* __restrict__ b_f1,
    const ushort* __restrict__ w_f2_b, const float* __restrict__ b_f2,
    float* __restrict__ out)
{
  extern __shared__ char smem[];
  ushort* rls = (ushort*)smem;                    // [64 px][256 c] swizzled
  ushort* hls = (ushort*)(smem + 64 * 256 * 2);

  const int tid = threadIdx.x, lane = tid & 63, wv = tid >> 6;
  const int n = lane & 15, q = lane >> 4;
  const int pix0 = blockIdx.x * 64;
  const int b = pix0 >> 12, hw0 = pix0 & 4095;
  const int sw = n & 7;
  const f32x4 zero = {0.f, 0.f, 0.f, 0.f};

  // ---- stage A: feat + residual -> r (bf16, LDS, swizzled [px][c]) ----
  {
    bf16x8 wa[8];
#pragma unroll
    for (int mt = 0; mt < 4; ++mt) {
      const int ob = wv * 64 + mt * 16;
      wa[mt * 2]     = *(const bf16x8*)(w_out_b + (ob + n) * 64 + q * 8);
      wa[mt * 2 + 1] = *(const bf16x8*)(w_out_b + (ob + n) * 64 + 32 + q * 8);
    }
    for (int nt = 0; nt < 4; ++nt) {
      const int px0 = nt * 16;
      const bf16x8 yb0 = *(const bf16x8*)(y + (size_t)(pix0 + px0 + n) * 64 + q * 8);
      const bf16x8 yb1 = *(const bf16x8*)(y + (size_t)(pix0 + px0 + n) * 64 + 32 + q * 8);
#pragma unroll
      for (int mt = 0; mt < 4; ++mt) {
        const int ob = wv * 64 + mt * 16;
        f32x4 acc = zero;
        acc = mfma16(wa[mt * 2], yb0, acc);
        acc = mfma16(wa[mt * 2 + 1], yb1, acc);
        const float4 sh = *(const float4*)(shift_o + ob + q * 4);
        const float sha[4] = {sh.x, sh.y, sh.z, sh.w};
        ushort tmp[4];
#pragma unroll
        for (int r = 0; r < 4; ++r) {
          const int o = ob + q * 4 + r;
          const float xv = x[(size_t)(b * 256 + o) * 4096 + hw0 + px0 + n];
          tmp[r] = f2bf(xv + acc[r] + sha[r]);
        }
        ushort4 v; v.x = tmp[0]; v.y = tmp[1]; v.z = tmp[2]; v.w = tmp[3];
        const int chunk = (ob >> 3) + (q >> 1);
        *(ushort4*)(rls + (px0 + n) * 256 + ((chunk ^ sw) * 8) + (q & 1) * 4) = v;
      }
    }
  }
  __syncthreads();

  // ---- stage B: h = relu(w_f1 @ r + b_f1) ----
  {
    bf16x8 wf[32];
#pragma unroll
    for (int mt = 0; mt < 4; ++mt)
#pragma unroll
      for (int kc = 0; kc < 8; ++kc)
        wf[mt * 8 + kc] = *(const bf16x8*)(w_f1_b + (size_t)(wv * 64 + mt * 16 + n) * 256 + kc * 32 + q * 8);
    for (int nt = 0; nt < 4; ++nt) {
      const int px0 = nt * 16;
      bf16x8 rb[8];
#pragma unroll
      for (int kc = 0; kc < 8; ++kc)
        rb[kc] = *(const bf16x8*)(rls + (px0 + n) * 256 + (((kc * 4 + q) ^ sw) * 8));
#pragma unroll
      for (int mt = 0; mt < 4; ++mt) {
        const int ob = wv * 64 + mt * 16;
        f32x4 a0 = zero, a1 = zero;
#pragma unroll
        for (int kc = 0; kc < 8; kc += 2) {
          a0 = mfma16(wf[mt * 8 + kc], rb[kc], a0);
          a1 = mfma16(wf[mt * 8 + kc + 1], rb[kc + 1], a1);
        }
        f32x4 acc = a0 + a1;
        const float4 bb = *(const float4*)(b_f1 + ob + q * 4);
        const float bba[4] = {bb.x, bb.y, bb.z, bb.w};
        ushort tmp[4];
#pragma unroll
        for (int r = 0; r < 4; ++r) tmp[r] = f2bf(fmaxf(acc[r] + bba[r], 0.0f));
        ushort4 v; v.x = tmp[0]; v.y = tmp[1]; v.z = tmp[2]; v.w = tmp[3];
        const int chunk = (ob >> 3) + (q >> 1);
        *(ushort4*)(hls + (px0 + n) * 256 + ((chunk ^ sw) * 8) + (q & 1) * 4) = v;
      }
    }
  }
  __syncthreads();

  // ---- stage C: out = w_f2 @ h + b_f2 (fp32 store) ----
  {
    bf16x8 wf[32];
#pragma unroll
    for (int mt = 0; mt < 4; ++mt)
#pragma unroll
      for (int kc = 0; kc < 8; ++kc)
        wf[mt * 8 + kc] = *(const bf16x8*)(w_f2_b + (size_t)(wv * 64 + mt * 16 + n) * 256 + kc * 32 + q * 8);
    for (int nt = 0; nt < 4; ++nt) {
      const int px0 = nt * 16;
      bf16x8 rb[8];
#pragma unroll
      for (int kc = 0; kc < 8; ++kc)
        rb[kc] = *(const bf16x8*)(hls + (px0 + n) * 256 + (((kc * 4 + q) ^ sw) * 8));
#pragma unroll
      for (int mt = 0; mt < 4; ++mt) {
        const int ob = wv * 64 + mt * 16;
        f32x4 a0 = zero, a1 = zero;
#pragma unroll
        for (int kc = 0; kc < 8; kc += 2) {
          a0 = mfma16(wf[mt * 8 + kc], rb[kc], a0);
          a1 = mfma16(wf[mt * 8 + kc + 1], rb[kc + 1], a1);
        }
        f32x4 acc = a0 + a1;
        const float4 bb = *(const float4*)(b_f2 + ob + q * 4);
        const float bba[4] = {bb.x, bb.y, bb.z, bb.w};
#pragma unroll
        for (int r = 0; r < 4; ++r) {
          const int o = ob + q * 4 + r;
          out[(size_t)(b * 256 + o) * 4096 + hw0 + px0 + n] = acc[r] + bba[r];
        }
      }
    }
  }
}

// ---------------------------------------------------------------------------
extern "C" void kernel_launch(void* const* d_in, const int* in_sizes, int n_in,
                              void* d_out, int out_size, void* d_ws, size_t ws_size,
                              hipStream_t stream) {
  const float* x     = (const float*)d_in[0];
  const float* w_red = (const float*)d_in[1];
  const float* w_c   = (const float*)d_in[2];
  const float* b_c   = (const float*)d_in[3];
  const float* bn_g  = (const float*)d_in[4];
  const float* bn_b  = (const float*)d_in[5];
  const float* bn_m  = (const float*)d_in[6];
  const float* bn_v  = (const float*)d_in[7];
  const float* w_out = (const float*)d_in[8];
  const float* b_out = (const float*)d_in[9];
  const float* bno_g = (const float*)d_in[10];
  const float* bno_b = (const float*)d_in[11];
  const float* bno_m = (const float*)d_in[12];
  const float* bno_v = (const float*)d_in[13];
  const float* w_f1  = (const float*)d_in[14];
  const float* b_f1  = (const float*)d_in[15];
  const float* w_f2  = (const float*)d_in[16];
  const float* b_f2  = (const float*)d_in[17];

  char* ws = (char*)d_ws;
  ushort* w_hi    = (ushort*)(ws + OFF_WHI);
  ushort* w_lo    = (ushort*)(ws + OFF_WLO);
  ushort* wc_b    = (ushort*)(ws + OFF_WCB);
  float*  shift_c = (float*)(ws + OFF_SHC);
  ushort* w_out_b = (ushort*)(ws + OFF_WOB);
  float*  shift_o = (float*)(ws + OFF_SHO);
  ushort* w_f1_b  = (ushort*)(ws + OFF_WF1);
  ushort* w_f2_b  = (ushort*)(ws + OFF_WF2);
  ushort* qnb     = (ushort*)(ws + OFF_QN);
  ushort* yb      = (ushort*)(ws + OFF_Y);

  k_prep<<<1074, 256, 0, stream>>>(w_red, w_c, b_c, bn_g, bn_b, bn_m, bn_v,
                                   w_out, b_out, bno_g, bno_b, bno_m, bno_v,
                                   w_f1, w_f2,
                                   w_hi, w_lo, wc_b, shift_c, w_out_b, shift_o, w_f1_b, w_f2_b);
  k_qnorm<<<512, 256, 0, stream>>>(x, w_hi, w_lo, qnb);
  k_encoder<<<dim3(16, 16, 8), 256, SMEM_ENC, stream>>>(qnb, wc_b, shift_c, yb);
  k_out<<<512, 256, SMEM_OUT, stream>>>(yb, x, w_out_b, shift_o, w_f1_b, b_f1, w_f2_b, b_f2,
                                        (float*)d_out);
}

// Round 15
// 270.236 us; speedup vs baseline: 1.3157x; 1.0216x over previous
//
#include <hip/hip_runtime.h>
#include <stdint.h>

// ---------------------------------------------------------------------------
// SSM: q=1x1 reduce + L2norm; ss = clamp(unfold7x7 * center); 3x chained 3x3
// conv (+BN+relu) per pixel; 1x1 + BN; residual; FFN (1x1,relu,1x1).
// B=8, C=256, MID=64, H=W=64.  bf16 MFMA 16x16x32 for all heavy GEMMs.
// R14: (a) encoder: s_setprio(1) around MFMA clusters (T5 — 2 independent
//      blocks/CU sit at different phases, the attn-like case). (b) k_out:
//      512 thr / 8 waves x 32 ch (same 64 px/WG, same weight traffic/WG as
//      R5 — avoids R6's failure), 4 waves/SIMD to hide scalar x/out latency.
//      Attribution preserved: encoder time is separately visible in counters.
// R9 measured neutral (qnorm MFMA kept: equal time, fewer VALU).  R8 base:
// 276.3 us = encoder 124.7 + residual 151.6.
// (Resubmitted unchanged after GPU-acquisition timeout.)
// ---------------------------------------------------------------------------

typedef __attribute__((ext_vector_type(8))) __bf16 bf16x8;
typedef __attribute__((ext_vector_type(4))) float f32x4;

__device__ __forceinline__ ushort f2bf(float f) {
  __bf16 h = (__bf16)f;                 // RNE, compiler packs pairs
  return __builtin_bit_cast(ushort, h);
}
__device__ __forceinline__ float bfu(ushort h) {
  return __builtin_bit_cast(float, ((uint32_t)h) << 16);
}
__device__ __forceinline__ f32x4 mfma16(bf16x8 a, bf16x8 b, f32x4 c) {
  return __builtin_amdgcn_mfma_f32_16x16x32_bf16(a, b, c, 0, 0, 0);
}

union BV8 { uint4 v; ushort u[8]; };
union BW8 { bf16x8 v; ushort u[8]; };

// ---------------------------------------------------------------------------
// Workspace layout (bytes)
// ---------------------------------------------------------------------------
#define OFF_WHI 0u          // w_hi     bf16 [64][256]            32768
#define OFF_WLO 32768u      // w_lo     bf16 [64][256]            32768
#define OFF_WCB 65536u      // wc_b     bf16 [3][9][64][64]       221184
#define OFF_SHC 286720u     // shift_c  fp32 [3][64]              768
#define OFF_WOB 287488u     // w_out_b  bf16 [256][64]            32768
#define OFF_SHO 320256u     // shift_o  fp32 [256]                1024
#define OFF_WF1 321280u     // w_f1_b   bf16 [256][256]           131072
#define OFF_WF2 452352u     // w_f2_b   bf16 [256][256]           131072
#define OFF_QN  583424u     // q_n      bf16 [32768][64]          4194304
#define OFF_Y   4777728u    // y        bf16 [32768][64]          4194304

// ---------------------------------------------------------------------------
// Kernel 0: weight prep (fold BN, transpose/split, cast to bf16)
// ---------------------------------------------------------------------------
__global__ __launch_bounds__(256) void k_prep(
    const float* __restrict__ w_red, const float* __restrict__ w_c, const float* __restrict__ b_c,
    const float* __restrict__ bn_g, const float* __restrict__ bn_b, const float* __restrict__ bn_m,
    const float* __restrict__ bn_v, const float* __restrict__ w_out, const float* __restrict__ b_out,
    const float* __restrict__ bno_g, const float* __restrict__ bno_b, const float* __restrict__ bno_m,
    const float* __restrict__ bno_v, const float* __restrict__ w_f1, const float* __restrict__ w_f2,
    ushort* __restrict__ w_hi, ushort* __restrict__ w_lo,
    ushort* __restrict__ wc_b, float* __restrict__ shift_c,
    ushort* __restrict__ w_out_b, float* __restrict__ shift_o,
    ushort* __restrict__ w_f1_b, ushort* __restrict__ w_f2_b)
{
  int i = blockIdx.x * 256 + threadIdx.x;
  if (i < 16384) {                       // split w_red[mid][c] -> hi/lo bf16
    float w = w_red[i];                  // i = mid*256 + c (row-major already)
    ushort h = f2bf(w);
    w_hi[i] = h;
    w_lo[i] = f2bf(w - bfu(h));
    return;
  }
  i -= 16384;
  if (i < 110592) {                      // wc_b[s][tap][o][c] = w_c[s][o][c][du][dv] * bnscale
    int c = i & 63, o = (i >> 6) & 63, st = i >> 12;
    int tap = st % 9, s = st / 9;
    float sc = bn_g[s * 64 + o] * rsqrtf(bn_v[s * 64 + o] + 1e-5f);
    wc_b[i] = f2bf(w_c[((s * 64 + o) * 64 + c) * 9 + tap] * sc);
    return;
  }
  i -= 110592;
  if (i < 192) {                         // shift_c[s][o]
    int s = i >> 6, o = i & 63;
    float sc = bn_g[s * 64 + o] * rsqrtf(bn_v[s * 64 + o] + 1e-5f);
    shift_c[i] = (b_c[i] - bn_m[i]) * sc + bn_b[i];
    return;
  }
  i -= 192;
  if (i < 16384) {                       // w_out_b[o][c] (bno scale folded)
    int o = i >> 6;
    float sc = bno_g[o] * rsqrtf(bno_v[o] + 1e-5f);
    w_out_b[i] = f2bf(w_out[i] * sc);
    return;
  }
  i -= 16384;
  if (i < 256) {                         // shift_o[o]
    float sc = bno_g[i] * rsqrtf(bno_v[i] + 1e-5f);
    shift_o[i] = (b_out[i] - bno_m[i]) * sc + bno_b[i];
    return;
  }
  i -= 256;
  if (i < 65536) { w_f1_b[i] = f2bf(w_f1[i]); return; }
  i -= 65536;
  if (i < 65536) { w_f2_b[i] = f2bf(w_f2[i]); return; }
}

// ---------------------------------------------------------------------------
// Kernel 1 (R9, measured neutral, kept): q = w_red @ x via MFMA, split-bf16.
// WG = 64 px, 4 waves x 16 px.  x fragments from global, no LDS/barriers.
// ---------------------------------------------------------------------------
__global__ __launch_bounds__(256) void k_qnorm(
    const float* __restrict__ x, const ushort* __restrict__ w_hi,
    const ushort* __restrict__ w_lo, ushort* __restrict__ qn)
{
  const int tid = threadIdx.x, lane = tid & 63, wv = tid >> 6;
  const int n = lane & 15, q = lane >> 4;
  const int pix0 = blockIdx.x * 64;
  const int b = pix0 >> 12, hw0 = pix0 & 4095;
  const int pxg = hw0 + wv * 16 + n;          // pixel within batch image
  const float* xb = x + (size_t)b * 256 * 4096 + pxg;

  const f32x4 zero = {0.f, 0.f, 0.f, 0.f};
  f32x4 acc[4] = {zero, zero, zero, zero};    // [mt] -> mids mt*16 + q*4 + r

#pragma unroll
  for (int kk = 0; kk < 8; ++kk) {
    const int cbase = kk * 32 + q * 8;        // 8 consecutive input channels
    float xv[8];
#pragma unroll
    for (int j = 0; j < 8; ++j)
      xv[j] = xb[(size_t)(cbase + j) * 4096];
    BW8 xh, xl;
#pragma unroll
    for (int j = 0; j < 8; ++j) {
      const ushort h = f2bf(xv[j]);           // hi = RNE bf16
      xh.u[j] = h;
      xl.u[j] = f2bf(xv[j] - bfu(h));         // lo = exact fp32 residual
    }
#pragma unroll
    for (int mt = 0; mt < 4; ++mt) {
      const bf16x8 wh = *(const bf16x8*)(w_hi + (mt * 16 + n) * 256 + cbase);
      const bf16x8 wl = *(const bf16x8*)(w_lo + (mt * 16 + n) * 256 + cbase);
      acc[mt] = mfma16(wh, xh.v, acc[mt]);
      acc[mt] = mfma16(wh, xl.v, acc[mt]);
      acc[mt] = mfma16(wl, xh.v, acc[mt]);
    }
  }

  // ---- L2 norm over 64 mids for px = n (lanes n, n^16, n^32 hold the rest)
  float s = 0.f;
#pragma unroll
  for (int mt = 0; mt < 4; ++mt)
#pragma unroll
    for (int r = 0; r < 4; ++r) s += acc[mt][r] * acc[mt][r];
  s += __shfl_xor(s, 16);
  s += __shfl_xor(s, 32);
  const float inv = 1.0f / fmaxf(sqrtf(s), 1e-12f);

#pragma unroll
  for (int mt = 0; mt < 4; ++mt) {
    ushort4 v;
    v.x = f2bf(acc[mt][0] * inv);
    v.y = f2bf(acc[mt][1] * inv);
    v.z = f2bf(acc[mt][2] * inv);
    v.w = f2bf(acc[mt][3] * inv);
    *(ushort4*)(qn + (size_t)(pix0 + wv * 16 + n) * 64 + mt * 16 + q * 4) = v;
  }
}

// ---------------------------------------------------------------------------
// Kernel 2: per-pixel encoder, streamed-ss (R6/R8 base, 124.7 us) + T5
// setprio around MFMA clusters (2 independent blocks/CU = phase-offset waves).
// ---------------------------------------------------------------------------
#define ENC_RING 7168              // ushorts per ring slot (7*16*64)
#define ENC_O1   14336             // ushort offset of o1
#define SMEM_ENC 79872             // bytes

__device__ __forceinline__ void store_act(ushort* buf, int pos, int n, int q, int o0,
                                          f32x4 acc, float4 sh) {
  ushort4 v;
  v.x = f2bf(fmaxf(acc[0] + sh.x, 0.0f));
  v.y = f2bf(fmaxf(acc[1] + sh.y, 0.0f));
  v.z = f2bf(fmaxf(acc[2] + sh.z, 0.0f));
  v.w = f2bf(fmaxf(acc[3] + sh.w, 0.0f));
  const int chunk = (o0 >> 3) + (q >> 1);
  *(ushort4*)(buf + (pos * 16 + n) * 64 + ((chunk ^ (n & 7)) * 8) + (q & 1) * 4) = v;
}

// Build one ss row (7 dv x 16 px x 64 ch) into a ring slot.
__device__ __forceinline__ void build_row(
    ushort* dstslot, const ushort* __restrict__ qn,
    int b, int tr, int tc, int ir, int tid)
{
  for (int u0 = tid; u0 < 896; u0 += 256) {
    const int ch = u0 & 7, px = (u0 >> 3) & 15, dv = u0 >> 7;
    const int ph = tr + (px >> 2), pw = tc + (px & 3);
    const int nh = ph + ir - 3, nw = pw + dv - 3;
    uint4 ov4;
    if ((unsigned)nh < 64u && (unsigned)nw < 64u) {
      BV8 cv; cv.v = *(const uint4*)(qn + (size_t)((b << 12) + ph * 64 + pw) * 64 + ch * 8);
      BV8 nv; nv.v = *(const uint4*)(qn + (size_t)((b << 12) + nh * 64 + nw) * 64 + ch * 8);
      BV8 ov;
#pragma unroll
      for (int j = 0; j < 8; ++j)
        ov.u[j] = f2bf(fmaxf(bfu(nv.u[j]) * bfu(cv.u[j]), 0.0f));
      ov4 = ov.v;
    } else {
      ov4 = make_uint4(0u, 0u, 0u, 0u);
    }
    *(uint4*)(dstslot + (dv * 16 + px) * 64 + ((ch ^ (px & 7)) * 8)) = ov4;
  }
}

__global__ __launch_bounds__(256, 2) void k_encoder(
    const ushort* __restrict__ qn, const ushort* __restrict__ wc_b,
    const float* __restrict__ shift_c, ushort* __restrict__ yout)
{
  extern __shared__ char smem[];
  ushort* enc = (ushort*)smem;        // ring slots at 0 / ENC_RING; o2 later at 0
  ushort* o1 = enc + ENC_O1;

  const int tid = threadIdx.x;
  const int b = blockIdx.z;
  const int tr = blockIdx.y * 4;
  const int tc = blockIdx.x * 4;

  const int lane = tid & 63, wv = tid >> 6;   // 4 waves
  const int n = lane & 15, q = lane >> 4;
  const int o0 = wv * 16;                     // o-tile (16 of 64 out-chan)
  const int sw = n & 7;
  const int rowoff = n * 64;
  const int c0 = ((0 + q) ^ sw) * 8;          // kc=0 chunk offset (ushorts)
  const int c1 = ((4 + q) ^ sw) * 8;          // kc=1 chunk offset

  // ---- conv1 weight A-fragments (persistent across all 7 rows) ----
  bf16x8 af[18];
#pragma unroll
  for (int t = 0; t < 9; ++t) {
    af[t * 2]     = *(const bf16x8*)(wc_b + (t * 64 + o0 + n) * 64 + q * 8);
    af[t * 2 + 1] = *(const bf16x8*)(wc_b + (t * 64 + o0 + n) * 64 + 32 + q * 8);
  }

  const f32x4 zero = {0.f, 0.f, 0.f, 0.f};
  f32x4 acc[5][5];
#pragma unroll
  for (int u = 0; u < 5; ++u)
#pragma unroll
    for (int v = 0; v < 5; ++v) acc[u][v] = zero;

  // ---- prologue: build ss row 0 ----
  build_row(enc, qn, b, tr, tc, 0, tid);
  __syncthreads();

  // ---- conv1 main loop: build row ir+1 while consuming row ir ----
#pragma unroll
  for (int ir = 0; ir < 7; ++ir) {
    if (ir < 6)
      build_row(enc + ((ir + 1) & 1) * ENC_RING, qn, b, tr, tc, ir + 1, tid);
    {
      const ushort* rowb = enc + (ir & 1) * ENC_RING + rowoff;
      bf16x8 rf0[7], rf1[7];
#pragma unroll
      for (int j = 0; j < 7; ++j) {
        rf0[j] = *(const bf16x8*)(rowb + j * 1024 + c0);
        rf1[j] = *(const bf16x8*)(rowb + j * 1024 + c1);
      }
      __builtin_amdgcn_s_setprio(1);
#pragma unroll
      for (int u = 0; u < 5; ++u) {
        const int du = ir - u;
        if (du >= 0 && du < 3) {
#pragma unroll
          for (int dv = 0; dv < 3; ++dv)
#pragma unroll
            for (int v = 0; v < 5; ++v) {
              acc[u][v] = mfma16(af[(du * 3 + dv) * 2],     rf0[v + dv], acc[u][v]);
              acc[u][v] = mfma16(af[(du * 3 + dv) * 2 + 1], rf1[v + dv], acc[u][v]);
            }
        }
      }
      __builtin_amdgcn_s_setprio(0);
    }
    if (ir < 6) __syncthreads();
  }

  // ---- conv1 epilogue: BN+relu -> o1 ----
  {
    const float4 sh = *(const float4*)(shift_c + o0 + q * 4);
#pragma unroll
    for (int u = 0; u < 5; ++u)
#pragma unroll
      for (int v = 0; v < 5; ++v)
        store_act(o1, u * 5 + v, n, q, o0, acc[u][v], sh);
  }
  __syncthreads();

  // ---- conv2: 3x3 outputs over 5x5 o1 (2D reuse), o2 -> ring region ----
  {
#pragma unroll
    for (int t = 0; t < 9; ++t) {
      af[t * 2]     = *(const bf16x8*)(wc_b + 9 * 4096 + (t * 64 + o0 + n) * 64 + q * 8);
      af[t * 2 + 1] = *(const bf16x8*)(wc_b + 9 * 4096 + (t * 64 + o0 + n) * 64 + 32 + q * 8);
    }
    f32x4 acc2[3][3];
#pragma unroll
    for (int u = 0; u < 3; ++u)
#pragma unroll
      for (int v = 0; v < 3; ++v) acc2[u][v] = zero;

    __builtin_amdgcn_s_setprio(1);
#pragma unroll
    for (int ir = 0; ir < 5; ++ir) {
      const ushort* rowb = o1 + ir * 5 * 1024 + rowoff;
      bf16x8 rf0[5], rf1[5];
#pragma unroll
      for (int j = 0; j < 5; ++j) {
        rf0[j] = *(const bf16x8*)(rowb + j * 1024 + c0);
        rf1[j] = *(const bf16x8*)(rowb + j * 1024 + c1);
      }
#pragma unroll
      for (int u = 0; u < 3; ++u) {
        const int du = ir - u;
        if (du >= 0 && du < 3) {
#pragma unroll
          for (int dv = 0; dv < 3; ++dv)
#pragma unroll
            for (int v = 0; v < 3; ++v) {
              acc2[u][v] = mfma16(af[(du * 3 + dv) * 2],     rf0[v + dv], acc2[u][v]);
              acc2[u][v] = mfma16(af[(du * 3 + dv) * 2 + 1], rf1[v + dv], acc2[u][v]);
            }
        }
      }
    }
    __builtin_amdgcn_s_setprio(0);
    const float4 sh = *(const float4*)(shift_c + 64 + o0 + q * 4);
#pragma unroll
    for (int u = 0; u < 3; ++u)
#pragma unroll
      for (int v = 0; v < 3; ++v)
        store_act(enc, u * 3 + v, n, q, o0, acc2[u][v], sh);
  }
  __syncthreads();

  // ---- conv3: 1 output over 3x3 o2 -> y (global), all 4 waves ----
  {
#pragma unroll
    for (int t = 0; t < 9; ++t) {
      af[t * 2]     = *(const bf16x8*)(wc_b + 18 * 4096 + (t * 64 + o0 + n) * 64 + q * 8);
      af[t * 2 + 1] = *(const bf16x8*)(wc_b + 18 * 4096 + (t * 64 + o0 + n) * 64 + 32 + q * 8);
    }
    f32x4 a0 = zero, a1 = zero;
    __builtin_amdgcn_s_setprio(1);
#pragma unroll
    for (int tap = 0; tap < 9; ++tap) {
      const ushort* rA = enc + tap * 1024 + rowoff;
      a0 = mfma16(af[tap * 2],     *(const bf16x8*)(rA + c0), a0);
      a1 = mfma16(af[tap * 2 + 1], *(const bf16x8*)(rA + c1), a1);
    }
    __builtin_amdgcn_s_setprio(0);
    f32x4 acc3 = a0 + a1;
    const float4 sh = *(const float4*)(shift_c + 128 + o0 + q * 4);
    ushort4 v;
    v.x = f2bf(fmaxf(acc3[0] + sh.x, 0.0f));
    v.y = f2bf(fmaxf(acc3[1] + sh.y, 0.0f));
    v.z = f2bf(fmaxf(acc3[2] + sh.z, 0.0f));
    v.w = f2bf(fmaxf(acc3[3] + sh.w, 0.0f));
    const int ph = tr + (n >> 2), pw = tc + (n & 3);
    *(ushort4*)(yout + (size_t)((b << 12) + ph * 64 + pw) * 64 + o0 + q * 4) = v;
  }
}

// ---------------------------------------------------------------------------
// Kernel 3 (R14): feat = BN(w_out@y); r = x + feat; out = FFN(r).
// WG = 64 pixels, 512 thr = 8 waves x 32 output channels (mt in {0,1}).
// Same px/WG and weight-traffic/WG as verified R5 shape; 2 blocks/CU ->
// 4 waves/SIMD to hide the scalar x-load / out-store latency.
// ---------------------------------------------------------------------------
#define SMEM_OUT (2 * 64 * 256 * 2)   // rls + hls = 65536 bytes

__global__ __launch_bounds__(512, 4) void k_out(
    const ushort* __restrict__ y, const float* __restrict__ x,
    const ushort* __restrict__ w_out_b, const float* __restrict__ shift_o,
    const ushort* __restrict__ w_f1_b, const float* __restrict__ b_f1,
    const ushort* __restrict__ w_f2_b, const float* __restrict__ b_f2,
    float* __restrict__ out)
{
  extern __shared__ char smem[];
  ushort* rls = (ushort*)smem;                    // [64 px][256 c] swizzled
  ushort* hls = (ushort*)(smem + 64 * 256 * 2);

  const int tid = threadIdx.x, lane = tid & 63, wv = tid >> 6;  // wv 0..7
  const int n = lane & 15, q = lane >> 4;
  const int pix0 = blockIdx.x * 64;
  const int b = pix0 >> 12, hw0 = pix0 & 4095;
  const int sw = n & 7;
  const f32x4 zero = {0.f, 0.f, 0.f, 0.f};

  // ---- stage A: feat + residual -> r (bf16, LDS, swizzled [px][c]) ----
  {
    bf16x8 wa[4];
#pragma unroll
    for (int mt = 0; mt < 2; ++mt) {
      const int ob = wv * 32 + mt * 16;
      wa[mt * 2]     = *(const bf16x8*)(w_out_b + (ob + n) * 64 + q * 8);
      wa[mt * 2 + 1] = *(const bf16x8*)(w_out_b + (ob + n) * 64 + 32 + q * 8);
    }
    for (int nt = 0; nt < 4; ++nt) {
      const int px0 = nt * 16;
      const bf16x8 yb0 = *(const bf16x8*)(y + (size_t)(pix0 + px0 + n) * 64 + q * 8);
      const bf16x8 yb1 = *(const bf16x8*)(y + (size_t)(pix0 + px0 + n) * 64 + 32 + q * 8);
#pragma unroll
      for (int mt = 0; mt < 2; ++mt) {
        const int ob = wv * 32 + mt * 16;
        f32x4 acc = zero;
        acc = mfma16(wa[mt * 2], yb0, acc);
        acc = mfma16(wa[mt * 2 + 1], yb1, acc);
        const float4 sh = *(const float4*)(shift_o + ob + q * 4);
        const float sha[4] = {sh.x, sh.y, sh.z, sh.w};
        ushort tmp[4];
#pragma unroll
        for (int r = 0; r < 4; ++r) {
          const int o = ob + q * 4 + r;
          const float xv = x[(size_t)(b * 256 + o) * 4096 + hw0 + px0 + n];
          tmp[r] = f2bf(xv + acc[r] + sha[r]);
        }
        ushort4 v; v.x = tmp[0]; v.y = tmp[1]; v.z = tmp[2]; v.w = tmp[3];
        const int chunk = (ob >> 3) + (q >> 1);
        *(ushort4*)(rls + (px0 + n) * 256 + ((chunk ^ sw) * 8) + (q & 1) * 4) = v;
      }
    }
  }
  __syncthreads();

  // ---- stage B: h = relu(w_f1 @ r + b_f1) ----
  {
    bf16x8 wf[16];
#pragma unroll
    for (int mt = 0; mt < 2; ++mt)
#pragma unroll
      for (int kc = 0; kc < 8; ++kc)
        wf[mt * 8 + kc] = *(const bf16x8*)(w_f1_b + (size_t)(wv * 32 + mt * 16 + n) * 256 + kc * 32 + q * 8);
    for (int nt = 0; nt < 4; ++nt) {
      const int px0 = nt * 16;
      bf16x8 rb[8];
#pragma unroll
      for (int kc = 0; kc < 8; ++kc)
        rb[kc] = *(const bf16x8*)(rls + (px0 + n) * 256 + (((kc * 4 + q) ^ sw) * 8));
#pragma unroll
      for (int mt = 0; mt < 2; ++mt) {
        const int ob = wv * 32 + mt * 16;
        f32x4 a0 = zero, a1 = zero;
#pragma unroll
        for (int kc = 0; kc < 8; kc += 2) {
          a0 = mfma16(wf[mt * 8 + kc], rb[kc], a0);
          a1 = mfma16(wf[mt * 8 + kc + 1], rb[kc + 1], a1);
        }
        f32x4 acc = a0 + a1;
        const float4 bb = *(const float4*)(b_f1 + ob + q * 4);
        const float bba[4] = {bb.x, bb.y, bb.z, bb.w};
        ushort tmp[4];
#pragma unroll
        for (int r = 0; r < 4; ++r) tmp[r] = f2bf(fmaxf(acc[r] + bba[r], 0.0f));
        ushort4 v; v.x = tmp[0]; v.y = tmp[1]; v.z = tmp[2]; v.w = tmp[3];
        const int chunk = (ob >> 3) + (q >> 1);
        *(ushort4*)(hls + (px0 + n) * 256 + ((chunk ^ sw) * 8) + (q & 1) * 4) = v;
      }
    }
  }
  __syncthreads();

  // ---- stage C: out = w_f2 @ h + b_f2 (fp32 store) ----
  {
    bf16x8 wf[16];
#pragma unroll
    for (int mt = 0; mt < 2; ++mt)
#pragma unroll
      for (int kc = 0; kc < 8; ++kc)
        wf[mt * 8 + kc] = *(const bf16x8*)(w_f2_b + (size_t)(wv * 32 + mt * 16 + n) * 256 + kc * 32 + q * 8);
    for (int nt = 0; nt < 4; ++nt) {
      const int px0 = nt * 16;
      bf16x8 rb[8];
#pragma unroll
      for (int kc = 0; kc < 8; ++kc)
        rb[kc] = *(const bf16x8*)(hls + (px0 + n) * 256 + (((kc * 4 + q) ^ sw) * 8));
#pragma unroll
      for (int mt = 0; mt < 2; ++mt) {
        const int ob = wv * 32 + mt * 16;
        f32x4 a0 = zero, a1 = zero;
#pragma unroll
        for (int kc = 0; kc < 8; kc += 2) {
          a0 = mfma16(wf[mt * 8 + kc], rb[kc], a0);
          a1 = mfma16(wf[mt * 8 + kc + 1], rb[kc + 1], a1);
        }
        f32x4 acc = a0 + a1;
        const float4 bb = *(const float4*)(b_f2 + ob + q * 4);
        const float bba[4] = {bb.x, bb.y, bb.z, bb.w};
#pragma unroll
        for (int r = 0; r < 4; ++r) {
          const int o = ob + q * 4 + r;
          out[(size_t)(b * 256 + o) * 4096 + hw0 + px0 + n] = acc[r] + bba[r];
        }
      }
    }
  }
}

// ---------------------------------------------------------------------------
extern "C" void kernel_launch(void* const* d_in, const int* in_sizes, int n_in,
                              void* d_out, int out_size, void* d_ws, size_t ws_size,
                              hipStream_t stream) {
  const float* x     = (const float*)d_in[0];
  const float* w_red = (const float*)d_in[1];
  const float* w_c   = (const float*)d_in[2];
  const float* b_c   = (const float*)d_in[3];
  const float* bn_g  = (const float*)d_in[4];
  const float* bn_b  = (const float*)d_in[5];
  const float* bn_m  = (const float*)d_in[6];
  const float* bn_v  = (const float*)d_in[7];
  const float* w_out = (const float*)d_in[8];
  const float* b_out = (const float*)d_in[9];
  const float* bno_g = (const float*)d_in[10];
  const float* bno_b = (const float*)d_in[11];
  const float* bno_m = (const float*)d_in[12];
  const float* bno_v = (const float*)d_in[13];
  const float* w_f1  = (const float*)d_in[14];
  const float* b_f1  = (const float*)d_in[15];
  const float* w_f2  = (const float*)d_in[16];
  const float* b_f2  = (const float*)d_in[17];

  char* ws = (char*)d_ws;
  ushort* w_hi    = (ushort*)(ws + OFF_WHI);
  ushort* w_lo    = (ushort*)(ws + OFF_WLO);
  ushort* wc_b    = (ushort*)(ws + OFF_WCB);
  float*  shift_c = (float*)(ws + OFF_SHC);
  ushort* w_out_b = (ushort*)(ws + OFF_WOB);
  float*  shift_o = (float*)(ws + OFF_SHO);
  ushort* w_f1_b  = (ushort*)(ws + OFF_WF1);
  ushort* w_f2_b  = (ushort*)(ws + OFF_WF2);
  ushort* qnb     = (ushort*)(ws + OFF_QN);
  ushort* yb      = (ushort*)(ws + OFF_Y);

  k_prep<<<1074, 256, 0, stream>>>(w_red, w_c, b_c, bn_g, bn_b, bn_m, bn_v,
                                   w_out, b_out, bno_g, bno_b, bno_m, bno_v,
                                   w_f1, w_f2,
                                   w_hi, w_lo, wc_b, shift_c, w_out_b, shift_o, w_f1_b, w_f2_b);
  k_qnorm<<<512, 256, 0, stream>>>(x, w_hi, w_lo, qnb);
  k_encoder<<<dim3(16, 16, 8), 256, SMEM_ENC, stream>>>(qnb, wc_b, shift_c, yb);
  k_out<<<512, 512, SMEM_OUT, stream>>>(yb, x, w_out_b, shift_o, w_f1_b, b_f1, w_f2_b, b_f2,
                                        (float*)d_out);
}

// Round 16
// 264.701 us; speedup vs baseline: 1.3433x; 1.0209x over previous
//
#include <hip/hip_runtime.h>
#include <stdint.h>

// ---------------------------------------------------------------------------
// SSM: q=1x1 reduce + L2norm; ss = clamp(unfold7x7 * center); 3x chained 3x3
// conv (+BN+relu) per pixel; 1x1 + BN; residual; FFN (1x1,relu,1x1).
// B=8, C=256, MID=64, H=W=64.  bf16 MFMA 16x16x32 for all heavy GEMMs.
// R16: revert encoder setprio (R14 measured it -5us: barrier-synced waves =
//      the lockstep-null case, not the attn case).  Keep R14 k_out 8-wave
//      (residual 151.1 -> 140.2, confirmed win) and R9 MFMA qnorm (neutral,
//      fewer VALU).  Encoder back to verified R8 body (125.0 us).
// ---------------------------------------------------------------------------

typedef __attribute__((ext_vector_type(8))) __bf16 bf16x8;
typedef __attribute__((ext_vector_type(4))) float f32x4;

__device__ __forceinline__ ushort f2bf(float f) {
  __bf16 h = (__bf16)f;                 // RNE, compiler packs pairs
  return __builtin_bit_cast(ushort, h);
}
__device__ __forceinline__ float bfu(ushort h) {
  return __builtin_bit_cast(float, ((uint32_t)h) << 16);
}
__device__ __forceinline__ f32x4 mfma16(bf16x8 a, bf16x8 b, f32x4 c) {
  return __builtin_amdgcn_mfma_f32_16x16x32_bf16(a, b, c, 0, 0, 0);
}

union BV8 { uint4 v; ushort u[8]; };
union BW8 { bf16x8 v; ushort u[8]; };

// ---------------------------------------------------------------------------
// Workspace layout (bytes)
// ---------------------------------------------------------------------------
#define OFF_WHI 0u          // w_hi     bf16 [64][256]            32768
#define OFF_WLO 32768u      // w_lo     bf16 [64][256]            32768
#define OFF_WCB 65536u      // wc_b     bf16 [3][9][64][64]       221184
#define OFF_SHC 286720u     // shift_c  fp32 [3][64]              768
#define OFF_WOB 287488u     // w_out_b  bf16 [256][64]            32768
#define OFF_SHO 320256u     // shift_o  fp32 [256]                1024
#define OFF_WF1 321280u     // w_f1_b   bf16 [256][256]           131072
#define OFF_WF2 452352u     // w_f2_b   bf16 [256][256]           131072
#define OFF_QN  583424u     // q_n      bf16 [32768][64]          4194304
#define OFF_Y   4777728u    // y        bf16 [32768][64]          4194304

// ---------------------------------------------------------------------------
// Kernel 0: weight prep (fold BN, transpose/split, cast to bf16)
// ---------------------------------------------------------------------------
__global__ __launch_bounds__(256) void k_prep(
    const float* __restrict__ w_red, const float* __restrict__ w_c, const float* __restrict__ b_c,
    const float* __restrict__ bn_g, const float* __restrict__ bn_b, const float* __restrict__ bn_m,
    const float* __restrict__ bn_v, const float* __restrict__ w_out, const float* __restrict__ b_out,
    const float* __restrict__ bno_g, const float* __restrict__ bno_b, const float* __restrict__ bno_m,
    const float* __restrict__ bno_v, const float* __restrict__ w_f1, const float* __restrict__ w_f2,
    ushort* __restrict__ w_hi, ushort* __restrict__ w_lo,
    ushort* __restrict__ wc_b, float* __restrict__ shift_c,
    ushort* __restrict__ w_out_b, float* __restrict__ shift_o,
    ushort* __restrict__ w_f1_b, ushort* __restrict__ w_f2_b)
{
  int i = blockIdx.x * 256 + threadIdx.x;
  if (i < 16384) {                       // split w_red[mid][c] -> hi/lo bf16
    float w = w_red[i];                  // i = mid*256 + c (row-major already)
    ushort h = f2bf(w);
    w_hi[i] = h;
    w_lo[i] = f2bf(w - bfu(h));
    return;
  }
  i -= 16384;
  if (i < 110592) {                      // wc_b[s][tap][o][c] = w_c[s][o][c][du][dv] * bnscale
    int c = i & 63, o = (i >> 6) & 63, st = i >> 12;
    int tap = st % 9, s = st / 9;
    float sc = bn_g[s * 64 + o] * rsqrtf(bn_v[s * 64 + o] + 1e-5f);
    wc_b[i] = f2bf(w_c[((s * 64 + o) * 64 + c) * 9 + tap] * sc);
    return;
  }
  i -= 110592;
  if (i < 192) {                         // shift_c[s][o]
    int s = i >> 6, o = i & 63;
    float sc = bn_g[s * 64 + o] * rsqrtf(bn_v[s * 64 + o] + 1e-5f);
    shift_c[i] = (b_c[i] - bn_m[i]) * sc + bn_b[i];
    return;
  }
  i -= 192;
  if (i < 16384) {                       // w_out_b[o][c] (bno scale folded)
    int o = i >> 6;
    float sc = bno_g[o] * rsqrtf(bno_v[o] + 1e-5f);
    w_out_b[i] = f2bf(w_out[i] * sc);
    return;
  }
  i -= 16384;
  if (i < 256) {                         // shift_o[o]
    float sc = bno_g[i] * rsqrtf(bno_v[i] + 1e-5f);
    shift_o[i] = (b_out[i] - bno_m[i]) * sc + bno_b[i];
    return;
  }
  i -= 256;
  if (i < 65536) { w_f1_b[i] = f2bf(w_f1[i]); return; }
  i -= 65536;
  if (i < 65536) { w_f2_b[i] = f2bf(w_f2[i]); return; }
}

// ---------------------------------------------------------------------------
// Kernel 1 (R9, measured neutral, kept): q = w_red @ x via MFMA, split-bf16.
// WG = 64 px, 4 waves x 16 px.  x fragments from global, no LDS/barriers.
// ---------------------------------------------------------------------------
__global__ __launch_bounds__(256) void k_qnorm(
    const float* __restrict__ x, const ushort* __restrict__ w_hi,
    const ushort* __restrict__ w_lo, ushort* __restrict__ qn)
{
  const int tid = threadIdx.x, lane = tid & 63, wv = tid >> 6;
  const int n = lane & 15, q = lane >> 4;
  const int pix0 = blockIdx.x * 64;
  const int b = pix0 >> 12, hw0 = pix0 & 4095;
  const int pxg = hw0 + wv * 16 + n;          // pixel within batch image
  const float* xb = x + (size_t)b * 256 * 4096 + pxg;

  const f32x4 zero = {0.f, 0.f, 0.f, 0.f};
  f32x4 acc[4] = {zero, zero, zero, zero};    // [mt] -> mids mt*16 + q*4 + r

#pragma unroll
  for (int kk = 0; kk < 8; ++kk) {
    const int cbase = kk * 32 + q * 8;        // 8 consecutive input channels
    float xv[8];
#pragma unroll
    for (int j = 0; j < 8; ++j)
      xv[j] = xb[(size_t)(cbase + j) * 4096];
    BW8 xh, xl;
#pragma unroll
    for (int j = 0; j < 8; ++j) {
      const ushort h = f2bf(xv[j]);           // hi = RNE bf16
      xh.u[j] = h;
      xl.u[j] = f2bf(xv[j] - bfu(h));         // lo = exact fp32 residual
    }
#pragma unroll
    for (int mt = 0; mt < 4; ++mt) {
      const bf16x8 wh = *(const bf16x8*)(w_hi + (mt * 16 + n) * 256 + cbase);
      const bf16x8 wl = *(const bf16x8*)(w_lo + (mt * 16 + n) * 256 + cbase);
      acc[mt] = mfma16(wh, xh.v, acc[mt]);
      acc[mt] = mfma16(wh, xl.v, acc[mt]);
      acc[mt] = mfma16(wl, xh.v, acc[mt]);
    }
  }

  // ---- L2 norm over 64 mids for px = n (lanes n, n^16, n^32 hold the rest)
  float s = 0.f;
#pragma unroll
  for (int mt = 0; mt < 4; ++mt)
#pragma unroll
    for (int r = 0; r < 4; ++r) s += acc[mt][r] * acc[mt][r];
  s += __shfl_xor(s, 16);
  s += __shfl_xor(s, 32);
  const float inv = 1.0f / fmaxf(sqrtf(s), 1e-12f);

#pragma unroll
  for (int mt = 0; mt < 4; ++mt) {
    ushort4 v;
    v.x = f2bf(acc[mt][0] * inv);
    v.y = f2bf(acc[mt][1] * inv);
    v.z = f2bf(acc[mt][2] * inv);
    v.w = f2bf(acc[mt][3] * inv);
    *(ushort4*)(qn + (size_t)(pix0 + wv * 16 + n) * 64 + mt * 16 + q * 4) = v;
  }
}

// ---------------------------------------------------------------------------
// Kernel 2: per-pixel encoder, streamed-ss version (R8 body, verified 125 us;
// R14's setprio reverted — barrier-synced waves are the lockstep-null case).
// WG = 16 pixels, 256 thr = 4 waves (1 o-tile each, perfectly balanced).
// LDS: ring[2][7 dv][16 px][64 ch] (28,672 B) + o1[25][16][64] (51,200 B)
//      = 79,872 B -> 2 blocks/CU.  o2 (9 pos, 18 KB) reuses ring region.
// conv1: per ir, build ss row ir+1 (global qn) while consuming row ir (MFMA).
// ---------------------------------------------------------------------------
#define ENC_RING 7168              // ushorts per ring slot (7*16*64)
#define ENC_O1   14336             // ushort offset of o1
#define SMEM_ENC 79872             // bytes

__device__ __forceinline__ void store_act(ushort* buf, int pos, int n, int q, int o0,
                                          f32x4 acc, float4 sh) {
  ushort4 v;
  v.x = f2bf(fmaxf(acc[0] + sh.x, 0.0f));
  v.y = f2bf(fmaxf(acc[1] + sh.y, 0.0f));
  v.z = f2bf(fmaxf(acc[2] + sh.z, 0.0f));
  v.w = f2bf(fmaxf(acc[3] + sh.w, 0.0f));
  const int chunk = (o0 >> 3) + (q >> 1);
  *(ushort4*)(buf + (pos * 16 + n) * 64 + ((chunk ^ (n & 7)) * 8) + (q & 1) * 4) = v;
}

// Build one ss row (7 dv x 16 px x 64 ch) into a ring slot.
__device__ __forceinline__ void build_row(
    ushort* dstslot, const ushort* __restrict__ qn,
    int b, int tr, int tc, int ir, int tid)
{
  for (int u0 = tid; u0 < 896; u0 += 256) {
    const int ch = u0 & 7, px = (u0 >> 3) & 15, dv = u0 >> 7;
    const int ph = tr + (px >> 2), pw = tc + (px & 3);
    const int nh = ph + ir - 3, nw = pw + dv - 3;
    uint4 ov4;
    if ((unsigned)nh < 64u && (unsigned)nw < 64u) {
      BV8 cv; cv.v = *(const uint4*)(qn + (size_t)((b << 12) + ph * 64 + pw) * 64 + ch * 8);
      BV8 nv; nv.v = *(const uint4*)(qn + (size_t)((b << 12) + nh * 64 + nw) * 64 + ch * 8);
      BV8 ov;
#pragma unroll
      for (int j = 0; j < 8; ++j)
        ov.u[j] = f2bf(fmaxf(bfu(nv.u[j]) * bfu(cv.u[j]), 0.0f));
      ov4 = ov.v;
    } else {
      ov4 = make_uint4(0u, 0u, 0u, 0u);
    }
    *(uint4*)(dstslot + (dv * 16 + px) * 64 + ((ch ^ (px & 7)) * 8)) = ov4;
  }
}

__global__ __launch_bounds__(256, 2) void k_encoder(
    const ushort* __restrict__ qn, const ushort* __restrict__ wc_b,
    const float* __restrict__ shift_c, ushort* __restrict__ yout)
{
  extern __shared__ char smem[];
  ushort* enc = (ushort*)smem;        // ring slots at 0 / ENC_RING; o2 later at 0
  ushort* o1 = enc + ENC_O1;

  const int tid = threadIdx.x;
  const int b = blockIdx.z;
  const int tr = blockIdx.y * 4;
  const int tc = blockIdx.x * 4;

  const int lane = tid & 63, wv = tid >> 6;   // 4 waves
  const int n = lane & 15, q = lane >> 4;
  const int o0 = wv * 16;                     // o-tile (16 of 64 out-chan)
  const int sw = n & 7;
  const int rowoff = n * 64;
  const int c0 = ((0 + q) ^ sw) * 8;          // kc=0 chunk offset (ushorts)
  const int c1 = ((4 + q) ^ sw) * 8;          // kc=1 chunk offset

  // ---- conv1 weight A-fragments (persistent across all 7 rows) ----
  bf16x8 af[18];
#pragma unroll
  for (int t = 0; t < 9; ++t) {
    af[t * 2]     = *(const bf16x8*)(wc_b + (t * 64 + o0 + n) * 64 + q * 8);
    af[t * 2 + 1] = *(const bf16x8*)(wc_b + (t * 64 + o0 + n) * 64 + 32 + q * 8);
  }

  const f32x4 zero = {0.f, 0.f, 0.f, 0.f};
  f32x4 acc[5][5];
#pragma unroll
  for (int u = 0; u < 5; ++u)
#pragma unroll
    for (int v = 0; v < 5; ++v) acc[u][v] = zero;

  // ---- prologue: build ss row 0 ----
  build_row(enc, qn, b, tr, tc, 0, tid);
  __syncthreads();

  // ---- conv1 main loop: build row ir+1 while consuming row ir ----
#pragma unroll
  for (int ir = 0; ir < 7; ++ir) {
    if (ir < 6)
      build_row(enc + ((ir + 1) & 1) * ENC_RING, qn, b, tr, tc, ir + 1, tid);
    {
      const ushort* rowb = enc + (ir & 1) * ENC_RING + rowoff;
      bf16x8 rf0[7], rf1[7];
#pragma unroll
      for (int j = 0; j < 7; ++j) {
        rf0[j] = *(const bf16x8*)(rowb + j * 1024 + c0);
        rf1[j] = *(const bf16x8*)(rowb + j * 1024 + c1);
      }
#pragma unroll
      for (int u = 0; u < 5; ++u) {
        const int du = ir - u;
        if (du >= 0 && du < 3) {
#pragma unroll
          for (int dv = 0; dv < 3; ++dv)
#pragma unroll
            for (int v = 0; v < 5; ++v) {
              acc[u][v] = mfma16(af[(du * 3 + dv) * 2],     rf0[v + dv], acc[u][v]);
              acc[u][v] = mfma16(af[(du * 3 + dv) * 2 + 1], rf1[v + dv], acc[u][v]);
            }
        }
      }
    }
    if (ir < 6) __syncthreads();
  }

  // ---- conv1 epilogue: BN+relu -> o1 ----
  {
    const float4 sh = *(const float4*)(shift_c + o0 + q * 4);
#pragma unroll
    for (int u = 0; u < 5; ++u)
#pragma unroll
      for (int v = 0; v < 5; ++v)
        store_act(o1, u * 5 + v, n, q, o0, acc[u][v], sh);
  }
  __syncthreads();

  // ---- conv2: 3x3 outputs over 5x5 o1 (2D reuse), o2 -> ring region ----
  {
#pragma unroll
    for (int t = 0; t < 9; ++t) {
      af[t * 2]     = *(const bf16x8*)(wc_b + 9 * 4096 + (t * 64 + o0 + n) * 64 + q * 8);
      af[t * 2 + 1] = *(const bf16x8*)(wc_b + 9 * 4096 + (t * 64 + o0 + n) * 64 + 32 + q * 8);
    }
    f32x4 acc2[3][3];
#pragma unroll
    for (int u = 0; u < 3; ++u)
#pragma unroll
      for (int v = 0; v < 3; ++v) acc2[u][v] = zero;

#pragma unroll
    for (int ir = 0; ir < 5; ++ir) {
      const ushort* rowb = o1 + ir * 5 * 1024 + rowoff;
      bf16x8 rf0[5], rf1[5];
#pragma unroll
      for (int j = 0; j < 5; ++j) {
        rf0[j] = *(const bf16x8*)(rowb + j * 1024 + c0);
        rf1[j] = *(const bf16x8*)(rowb + j * 1024 + c1);
      }
#pragma unroll
      for (int u = 0; u < 3; ++u) {
        const int du = ir - u;
        if (du >= 0 && du < 3) {
#pragma unroll
          for (int dv = 0; dv < 3; ++dv)
#pragma unroll
            for (int v = 0; v < 3; ++v) {
              acc2[u][v] = mfma16(af[(du * 3 + dv) * 2],     rf0[v + dv], acc2[u][v]);
              acc2[u][v] = mfma16(af[(du * 3 + dv) * 2 + 1], rf1[v + dv], acc2[u][v]);
            }
        }
      }
    }
    const float4 sh = *(const float4*)(shift_c + 64 + o0 + q * 4);
#pragma unroll
    for (int u = 0; u < 3; ++u)
#pragma unroll
      for (int v = 0; v < 3; ++v)
        store_act(enc, u * 3 + v, n, q, o0, acc2[u][v], sh);
  }
  __syncthreads();

  // ---- conv3: 1 output over 3x3 o2 -> y (global), all 4 waves ----
  {
#pragma unroll
    for (int t = 0; t < 9; ++t) {
      af[t * 2]     = *(const bf16x8*)(wc_b + 18 * 4096 + (t * 64 + o0 + n) * 64 + q * 8);
      af[t * 2 + 1] = *(const bf16x8*)(wc_b + 18 * 4096 + (t * 64 + o0 + n) * 64 + 32 + q * 8);
    }
    f32x4 a0 = zero, a1 = zero;
#pragma unroll
    for (int tap = 0; tap < 9; ++tap) {
      const ushort* rA = enc + tap * 1024 + rowoff;
      a0 = mfma16(af[tap * 2],     *(const bf16x8*)(rA + c0), a0);
      a1 = mfma16(af[tap * 2 + 1], *(const bf16x8*)(rA + c1), a1);
    }
    f32x4 acc3 = a0 + a1;
    const float4 sh = *(const float4*)(shift_c + 128 + o0 + q * 4);
    ushort4 v;
    v.x = f2bf(fmaxf(acc3[0] + sh.x, 0.0f));
    v.y = f2bf(fmaxf(acc3[1] + sh.y, 0.0f));
    v.z = f2bf(fmaxf(acc3[2] + sh.z, 0.0f));
    v.w = f2bf(fmaxf(acc3[3] + sh.w, 0.0f));
    const int ph = tr + (n >> 2), pw = tc + (n & 3);
    *(ushort4*)(yout + (size_t)((b << 12) + ph * 64 + pw) * 64 + o0 + q * 4) = v;
  }
}

// ---------------------------------------------------------------------------
// Kernel 3 (R14, verified -10.9 us): feat = BN(w_out@y); r = x + feat;
// out = FFN(r).  WG = 64 pixels, 512 thr = 8 waves x 32 output channels.
// Same px/WG and weight-traffic/WG as R5 shape; 2 blocks/CU -> 4 waves/SIMD
// hides the scalar x-load / out-store latency.
// ---------------------------------------------------------------------------
#define SMEM_OUT (2 * 64 * 256 * 2)   // rls + hls = 65536 bytes

__global__ __launch_bounds__(512, 4) void k_out(
    const ushort* __restrict__ y, const float* __restrict__ x,
    const ushort* __restrict__ w_out_b, const float* __restrict__ shift_o,
    const ushort* __restrict__ w_f1_b, const float* __restrict__ b_f1,
    const ushort* __restrict__ w_f2_b, const float* __restrict__ b_f2,
    float* __restrict__ out)
{
  extern __shared__ char smem[];
  ushort* rls = (ushort*)smem;                    // [64 px][256 c] swizzled
  ushort* hls = (ushort*)(smem + 64 * 256 * 2);

  const int tid = threadIdx.x, lane = tid & 63, wv = tid >> 6;  // wv 0..7
  const int n = lane & 15, q = lane >> 4;
  const int pix0 = blockIdx.x * 64;
  const int b = pix0 >> 12, hw0 = pix0 & 4095;
  const int sw = n & 7;
  const f32x4 zero = {0.f, 0.f, 0.f, 0.f};

  // ---- stage A: feat + residual -> r (bf16, LDS, swizzled [px][c]) ----
  {
    bf16x8 wa[4];
#pragma unroll
    for (int mt = 0; mt < 2; ++mt) {
      const int ob = wv * 32 + mt * 16;
      wa[mt * 2]     = *(const bf16x8*)(w_out_b + (ob + n) * 64 + q * 8);
      wa[mt * 2 + 1] = *(const bf16x8*)(w_out_b + (ob + n) * 64 + 32 + q * 8);
    }
    for (int nt = 0; nt < 4; ++nt) {
      const int px0 = nt * 16;
      const bf16x8 yb0 = *(const bf16x8*)(y + (size_t)(pix0 + px0 + n) * 64 + q * 8);
      const bf16x8 yb1 = *(const bf16x8*)(y + (size_t)(pix0 + px0 + n) * 64 + 32 + q * 8);
#pragma unroll
      for (int mt = 0; mt < 2; ++mt) {
        const int ob = wv * 32 + mt * 16;
        f32x4 acc = zero;
        acc = mfma16(wa[mt * 2], yb0, acc);
        acc = mfma16(wa[mt * 2 + 1], yb1, acc);
        const float4 sh = *(const float4*)(shift_o + ob + q * 4);
        const float sha[4] = {sh.x, sh.y, sh.z, sh.w};
        ushort tmp[4];
#pragma unroll
        for (int r = 0; r < 4; ++r) {
          const int o = ob + q * 4 + r;
          const float xv = x[(size_t)(b * 256 + o) * 4096 + hw0 + px0 + n];
          tmp[r] = f2bf(xv + acc[r] + sha[r]);
        }
        ushort4 v; v.x = tmp[0]; v.y = tmp[1]; v.z = tmp[2]; v.w = tmp[3];
        const int chunk = (ob >> 3) + (q >> 1);
        *(ushort4*)(rls + (px0 + n) * 256 + ((chunk ^ sw) * 8) + (q & 1) * 4) = v;
      }
    }
  }
  __syncthreads();

  // ---- stage B: h = relu(w_f1 @ r + b_f1) ----
  {
    bf16x8 wf[16];
#pragma unroll
    for (int mt = 0; mt < 2; ++mt)
#pragma unroll
      for (int kc = 0; kc < 8; ++kc)
        wf[mt * 8 + kc] = *(const bf16x8*)(w_f1_b + (size_t)(wv * 32 + mt * 16 + n) * 256 + kc * 32 + q * 8);
    for (int nt = 0; nt < 4; ++nt) {
      const int px0 = nt * 16;
      bf16x8 rb[8];
#pragma unroll
      for (int kc = 0; kc < 8; ++kc)
        rb[kc] = *(const bf16x8*)(rls + (px0 + n) * 256 + (((kc * 4 + q) ^ sw) * 8));
#pragma unroll
      for (int mt = 0; mt < 2; ++mt) {
        const int ob = wv * 32 + mt * 16;
        f32x4 a0 = zero, a1 = zero;
#pragma unroll
        for (int kc = 0; kc < 8; kc += 2) {
          a0 = mfma16(wf[mt * 8 + kc], rb[kc], a0);
          a1 = mfma16(wf[mt * 8 + kc + 1], rb[kc + 1], a1);
        }
        f32x4 acc = a0 + a1;
        const float4 bb = *(const float4*)(b_f1 + ob + q * 4);
        const float bba[4] = {bb.x, bb.y, bb.z, bb.w};
        ushort tmp[4];
#pragma unroll
        for (int r = 0; r < 4; ++r) tmp[r] = f2bf(fmaxf(acc[r] + bba[r], 0.0f));
        ushort4 v; v.x = tmp[0]; v.y = tmp[1]; v.z = tmp[2]; v.w = tmp[3];
        const int chunk = (ob >> 3) + (q >> 1);
        *(ushort4*)(hls + (px0 + n) * 256 + ((chunk ^ sw) * 8) + (q & 1) * 4) = v;
      }
    }
  }
  __syncthreads();

  // ---- stage C: out = w_f2 @ h + b_f2 (fp32 store) ----
  {
    bf16x8 wf[16];
#pragma unroll
    for (int mt = 0; mt < 2; ++mt)
#pragma unroll
      for (int kc = 0; kc < 8; ++kc)
        wf[mt * 8 + kc] = *(const bf16x8*)(w_f2_b + (size_t)(wv * 32 + mt * 16 + n) * 256 + kc * 32 + q * 8);
    for (int nt = 0; nt < 4; ++nt) {
      const int px0 = nt * 16;
      bf16x8 rb[8];
#pragma unroll
      for (int kc = 0; kc < 8; ++kc)
        rb[kc] = *(const bf16x8*)(hls + (px0 + n) * 256 + (((kc * 4 + q) ^ sw) * 8));
#pragma unroll
      for (int mt = 0; mt < 2; ++mt) {
        const int ob = wv * 32 + mt * 16;
        f32x4 a0 = zero, a1 = zero;
#pragma unroll
        for (int kc = 0; kc < 8; kc += 2) {
          a0 = mfma16(wf[mt * 8 + kc], rb[kc], a0);
          a1 = mfma16(wf[mt * 8 + kc + 1], rb[kc + 1], a1);
        }
        f32x4 acc = a0 + a1;
        const float4 bb = *(const float4*)(b_f2 + ob + q * 4);
        const float bba[4] = {bb.x, bb.y, bb.z, bb.w};
#pragma unroll
        for (int r = 0; r < 4; ++r) {
          const int o = ob + q * 4 + r;
          out[(size_t)(b * 256 + o) * 4096 + hw0 + px0 + n] = acc[r] + bba[r];
        }
      }
    }
  }
}

// ---------------------------------------------------------------------------
extern "C" void kernel_launch(void* const* d_in, const int* in_sizes, int n_in,
                              void* d_out, int out_size, void* d_ws, size_t ws_size,
                              hipStream_t stream) {
  const float* x     = (const float*)d_in[0];
  const float* w_red = (const float*)d_in[1];
  const float* w_c   = (const float*)d_in[2];
  const float* b_c   = (const float*)d_in[3];
  const float* bn_g  = (const float*)d_in[4];
  const float* bn_b  = (const float*)d_in[5];
  const float* bn_m  = (const float*)d_in[6];
  const float* bn_v  = (const float*)d_in[7];
  const float* w_out = (const float*)d_in[8];
  const float* b_out = (const float*)d_in[9];
  const float* bno_g = (const float*)d_in[10];
  const float* bno_b = (const float*)d_in[11];
  const float* bno_m = (const float*)d_in[12];
  const float* bno_v = (const float*)d_in[13];
  const float* w_f1  = (const float*)d_in[14];
  const float* b_f1  = (const float*)d_in[15];
  const float* w_f2  = (const float*)d_in[16];
  const float* b_f2  = (const float*)d_in[17];

  char* ws = (char*)d_ws;
  ushort* w_hi    = (ushort*)(ws + OFF_WHI);
  ushort* w_lo    = (ushort*)(ws + OFF_WLO);
  ushort* wc_b    = (ushort*)(ws + OFF_WCB);
  float*  shift_c = (float*)(ws + OFF_SHC);
  ushort* w_out_b = (ushort*)(ws + OFF_WOB);
  float*  shift_o = (float*)(ws + OFF_SHO);
  ushort* w_f1_b  = (ushort*)(ws + OFF_WF1);
  ushort* w_f2_b  = (ushort*)(ws + OFF_WF2);
  ushort* qnb     = (ushort*)(ws + OFF_QN);
  ushort* yb      = (ushort*)(ws + OFF_Y);

  k_prep<<<1074, 256, 0, stream>>>(w_red, w_c, b_c, bn_g, bn_b, bn_m, bn_v,
                                   w_out, b_out, bno_g, bno_b, bno_m, bno_v,
                                   w_f1, w_f2,
                                   w_hi, w_lo, wc_b, shift_c, w_out_b, shift_o, w_f1_b, w_f2_b);
  k_qnorm<<<512, 256, 0, stream>>>(x, w_hi, w_lo, qnb);
  k_encoder<<<dim3(16, 16, 8), 256, SMEM_ENC, stream>>>(qnb, wc_b, shift_c, yb);
  k_out<<<512, 512, SMEM_OUT, stream>>>(yb, x, w_out_b, shift_o, w_f1_b, b_f1, w_f2_b, b_f2,
                                        (float*)d_out);
}